// Round 1
// baseline (5571.897 us; speedup 1.0000x reference)
//
#include <hip/hip_runtime.h>
#include <math.h>

#define IMG   160
#define HWSZ  25600
#define NB    4
#define CIN   256
#define COUT1 384
#define BIGK  90000

// output offsets (in floats)
#define OFF_LMAP 0
#define OFF_JMAP 102400
#define OFF_JOFF 204800
#define OFF_CMAP 409600
#define OFF_COFF 512000
#define OFF_LVEC 716800
#define OFF_LOI  1126400
#define OFF_MASK 1206400

// workspace offsets (bytes)
static const size_t WS_Y1    = 0;
static const size_t WS_JSORT = (size_t)NB * COUT1 * HWSZ * 4;            // 157286400
static const size_t WS_CSORT = WS_JSORT + (size_t)NB * 32768 * 8;
static const size_t WS_JUNC  = WS_CSORT + (size_t)NB * 32768 * 8;
static const size_t WS_JVAL  = WS_JUNC + (size_t)NB * 300 * 2 * 4;
static const size_t WS_LKEY  = WS_JVAL + (size_t)NB * 300 * 4;
static const size_t WS_NEED  = WS_LKEY + (size_t)NB * 8192 * 4;

__device__ __forceinline__ float clip_coord(float v) {
    return fminf(fmaxf(v, 0.0f), 159.9999f);
}

__device__ __forceinline__ float sigmoidf(float v) {
    return 1.0f / (1.0f + expf(-v));
}

// ---------------------------------------------------------------------------
// conv1 (3x3, 256->384) + BN + ReLU.  Block = 16x16 pixels, 32 output channels.
// Weights are wave-uniform -> scalar loads; input tile staged in LDS.
// ---------------------------------------------------------------------------
__global__ __launch_bounds__(256) void conv1_kernel(
    const float* __restrict__ feat, const float* __restrict__ w1,
    const float* __restrict__ b1, const float* __restrict__ gamma,
    const float* __restrict__ beta, const float* __restrict__ mean,
    const float* __restrict__ var, float* __restrict__ y1) {
    const int bz  = blockIdx.z;
    const int b   = bz / 12;
    const int oc0 = (bz % 12) * 32;
    const int tx  = blockIdx.x * 16, ty = blockIdx.y * 16;
    const int lx  = threadIdx.x, ly = threadIdx.y;
    const int tid = ly * 16 + lx;

    __shared__ float tin[18][20];
    float acc[32];
#pragma unroll
    for (int o = 0; o < 32; ++o) acc[o] = 0.0f;

    for (int ic = 0; ic < CIN; ++ic) {
        const float* src = feat + ((size_t)(b * CIN + ic)) * HWSZ;
        for (int i = tid; i < 324; i += 256) {
            int r = i / 18, c = i % 18;
            int gy = ty - 1 + r, gx = tx - 1 + c;
            tin[r][c] = (gy >= 0 && gy < IMG && gx >= 0 && gx < IMG)
                            ? src[gy * IMG + gx] : 0.0f;
        }
        __syncthreads();
        float n0 = tin[ly][lx],     n1 = tin[ly][lx + 1],     n2 = tin[ly][lx + 2];
        float n3 = tin[ly + 1][lx], n4 = tin[ly + 1][lx + 1], n5 = tin[ly + 1][lx + 2];
        float n6 = tin[ly + 2][lx], n7 = tin[ly + 2][lx + 1], n8 = tin[ly + 2][lx + 2];
        const float* wbase = w1 + ((size_t)oc0 * CIN + ic) * 9;
#pragma unroll
        for (int o = 0; o < 32; ++o) {
            const float* wp = wbase + (size_t)o * (CIN * 9);
            acc[o] += n0 * wp[0] + n1 * wp[1] + n2 * wp[2]
                    + n3 * wp[3] + n4 * wp[4] + n5 * wp[5]
                    + n6 * wp[6] + n7 * wp[7] + n8 * wp[8];
        }
        __syncthreads();
    }

    const int oy = ty + ly, ox = tx + lx;
#pragma unroll
    for (int o = 0; o < 32; ++o) {
        int oc  = oc0 + o;
        float v = acc[o] + b1[oc];
        v = (v - mean[oc]) * (gamma[oc] / sqrtf(var[oc] + 1e-5f)) + beta[oc];
        v = fmaxf(v, 0.0f);
        y1[((size_t)(b * COUT1 + oc)) * HWSZ + oy * IMG + ox] = v;
    }
}

// ---------------------------------------------------------------------------
// conv2: grouped 3x3, per head only the SEL output channels; writes maps
// (with sigmoid where required) straight into d_out.
// ---------------------------------------------------------------------------
__global__ __launch_bounds__(256) void conv2_kernel(
    const float* __restrict__ y1, const float* __restrict__ w2,
    const float* __restrict__ b2, float* __restrict__ out) {
    const int KH[6]   = {1, 1, 2, 1, 2, 4};
    const int REG[6]  = {OFF_LMAP, OFF_JMAP, OFF_JOFF, OFF_CMAP, OFF_COFF, OFF_LVEC};
    const int SIGF[6] = {1, 1, 0, 1, 0, 0};

    const int bz = blockIdx.z;
    const int b  = bz / 6;
    const int h  = bz % 6;
    const int k  = KH[h];
    const int tx = blockIdx.x * 16, ty = blockIdx.y * 16;
    const int lx = threadIdx.x, ly = threadIdx.y;
    const int tid = ly * 16 + lx;

    __shared__ float tin[18][20];
    float acc[4] = {0.0f, 0.0f, 0.0f, 0.0f};

    for (int icl = 0; icl < 64; ++icl) {
        const int ch = h * 64 + icl;
        const float* src = y1 + ((size_t)(b * COUT1 + ch)) * HWSZ;
        for (int i = tid; i < 324; i += 256) {
            int r = i / 18, c = i % 18;
            int gy = ty - 1 + r, gx = tx - 1 + c;
            tin[r][c] = (gy >= 0 && gy < IMG && gx >= 0 && gx < IMG)
                            ? src[gy * IMG + gx] : 0.0f;
        }
        __syncthreads();
        float n0 = tin[ly][lx],     n1 = tin[ly][lx + 1],     n2 = tin[ly][lx + 2];
        float n3 = tin[ly + 1][lx], n4 = tin[ly + 1][lx + 1], n5 = tin[ly + 1][lx + 2];
        float n6 = tin[ly + 2][lx], n7 = tin[ly + 2][lx + 1], n8 = tin[ly + 2][lx + 2];
#pragma unroll
        for (int o = 0; o < 4; ++o) {
            if (o < k) {
                const float* wp = w2 + ((size_t)((h * 4 + o) * 64 + icl)) * 9;
                acc[o] += n0 * wp[0] + n1 * wp[1] + n2 * wp[2]
                        + n3 * wp[3] + n4 * wp[4] + n5 * wp[5]
                        + n6 * wp[6] + n7 * wp[7] + n8 * wp[8];
            }
        }
        __syncthreads();
    }

    const int p = (ty + ly) * IMG + tx + lx;
    for (int o = 0; o < k; ++o) {
        float v = acc[o] + b2[h * 4 + o];
        if (SIGF[h]) v = sigmoidf(v);
        out[REG[h] + ((size_t)(b * k + o)) * HWSZ + p] = v;
    }
}

// ---------------------------------------------------------------------------
// NMS on jmap + pack sort keys for jmap(NMS) and cmap.
// key = value_bits<<32 | (~index)  -> descending sort == lax.top_k order
// (stable: ties broken by lower index first).
// ---------------------------------------------------------------------------
__global__ void nms_pack_kernel(const float* __restrict__ out,
                                unsigned long long* __restrict__ jsort,
                                unsigned long long* __restrict__ csort) {
    const int g = blockIdx.x;           // 0..399
    const int b = g / 100, q = g % 100;
    const int p = q * 256 + threadIdx.x;
    const float* jm = out + OFF_JMAP + (size_t)b * HWSZ;
    const float* cm = out + OFF_CMAP + (size_t)b * HWSZ;

    const int x = p % IMG, y = p / IMG;
    float v = jm[p];
    float mx = v;
#pragma unroll
    for (int dy = -1; dy <= 1; ++dy)
#pragma unroll
        for (int dx = -1; dx <= 1; ++dx) {
            int nx = x + dx, ny = y + dy;
            if (nx >= 0 && nx < IMG && ny >= 0 && ny < IMG)
                mx = fmaxf(mx, jm[ny * IMG + nx]);
        }
    float nmsv = (v == mx) ? v : 0.0f;

    unsigned long long tagj = ((unsigned long long)__float_as_uint(nmsv) << 32)
                            | (unsigned long long)(0xFFFFFFFFu - (unsigned)p);
    unsigned long long tagc = ((unsigned long long)__float_as_uint(cm[p]) << 32)
                            | (unsigned long long)(0xFFFFFFFFu - (unsigned)p);
    jsort[(size_t)b * 32768 + p] = tagj;
    csort[(size_t)b * 32768 + p] = tagc;
    if (q < 28) {                        // pad 25600..32767 with minimal keys
        int pp = 25600 + q * 256 + threadIdx.x;
        if (pp < 32768) {
            jsort[(size_t)b * 32768 + pp] = 0ull;
            csort[(size_t)b * 32768 + pp] = 0ull;
        }
    }
}

// Single-block bitonic sort, descending, 32768 u64 keys (one array per block).
__global__ __launch_bounds__(1024) void sort64_desc_kernel(unsigned long long* __restrict__ buf) {
    unsigned long long* a = buf + (size_t)blockIdx.x * 32768;
    const int N = 32768;
    for (int k = 2; k <= N; k <<= 1)
        for (int j = k >> 1; j > 0; j >>= 1) {
            __syncthreads();
            for (int i = threadIdx.x; i < N; i += 1024) {
                int l = i ^ j;
                if (l > i) {
                    unsigned long long x = a[i], y = a[l];
                    bool desc = ((i & k) == 0);
                    if (desc ? (x < y) : (x > y)) { a[i] = y; a[l] = x; }
                }
            }
        }
}

// Single-block bitonic sort, ascending, 8192 int keys.
__global__ __launch_bounds__(1024) void sort32_asc_kernel(int* __restrict__ buf) {
    int* a = buf + (size_t)blockIdx.x * 8192;
    const int N = 8192;
    for (int k = 2; k <= N; k <<= 1)
        for (int j = k >> 1; j > 0; j >>= 1) {
            __syncthreads();
            for (int i = threadIdx.x; i < N; i += 1024) {
                int l = i ^ j;
                if (l > i) {
                    int x = a[i], y = a[l];
                    bool asc = ((i & k) == 0);
                    if (asc ? (x > y) : (x < y)) { a[i] = y; a[l] = x; }
                }
            }
        }
}

// Top-300 junctions: coordinates + validity.
__global__ void junction_kernel(const unsigned long long* __restrict__ jsort,
                                const float* __restrict__ out,
                                float* __restrict__ junc, int* __restrict__ jvalid) {
    const int b = blockIdx.x;
    const int t = threadIdx.x;
    if (t >= 300) return;
    unsigned long long key = jsort[(size_t)b * 32768 + t];
    float score  = __uint_as_float((unsigned)(key >> 32));
    unsigned idx = 0xFFFFFFFFu - (unsigned)(key & 0xFFFFFFFFull);
    const float* j0 = out + OFF_JOFF + (size_t)(b * 2) * HWSZ;
    const float* j1 = j0 + HWSZ;
    float jx = (float)(idx % IMG) + j0[idx] + 0.5f;
    float jy = (float)(idx / IMG) + j1[idx] + 0.5f;
    junc[(size_t)(b * 300 + t) * 2]     = clip_coord(jx);
    junc[(size_t)(b * 300 + t) * 2 + 1] = clip_coord(jy);
    jvalid[b * 300 + t] = (score >= 0.008f) ? 1 : 0;
}

// Top-5000 centers -> line endpoints -> nearest-junction keys.
__global__ void lines_kernel(const unsigned long long* __restrict__ csort,
                             const float* __restrict__ junc,
                             const int* __restrict__ jvalid,
                             const float* __restrict__ out,
                             int* __restrict__ lkeys) {
    const int b = blockIdx.y;
    const int t = blockIdx.x * 256 + threadIdx.x;

    __shared__ float jx[300], jy[300];
    __shared__ int jv[300];
    for (int i = threadIdx.x; i < 300; i += 256) {
        jx[i] = junc[(size_t)(b * 300 + i) * 2];
        jy[i] = junc[(size_t)(b * 300 + i) * 2 + 1];
        jv[i] = jvalid[b * 300 + i];
    }
    __syncthreads();

    if (t >= 8192) return;
    if (t >= 5000) { lkeys[b * 8192 + t] = 0x7FFFFFFF; return; }

    unsigned long long key = csort[(size_t)b * 32768 + t];
    unsigned idx = 0xFFFFFFFFu - (unsigned)(key & 0xFFFFFFFFull);
    const float* c0 = out + OFF_COFF + (size_t)(b * 2) * HWSZ;
    const float* c1 = c0 + HWSZ;
    const float* lv = out + OFF_LVEC + (size_t)(b * 4) * HWSZ;

    float cx = (float)(idx % IMG) + c0[idx] + 0.5f;
    float cy = (float)(idx / IMG) + c1[idx] + 0.5f;
    float e0x = clip_coord(cx + lv[idx]);
    float e0y = clip_coord(cy + lv[HWSZ + idx]);
    float e1x = clip_coord(cx + lv[2 * HWSZ + idx]);
    float e1y = clip_coord(cy + lv[3 * HWSZ + idx]);

    float m1 = 1e18f, m2 = 1e18f;
    int i1 = 0, i2 = 0;
    for (int j = 0; j < 300; ++j) {
        if (jv[j]) {
            float dx = e0x - jx[j], dy = e0y - jy[j];
            float d = dx * dx + dy * dy;
            if (d < m1) { m1 = d; i1 = j; }
            dx = e1x - jx[j]; dy = e1y - jy[j];
            d = dx * dx + dy * dy;
            if (d < m2) { m2 = d; i2 = j; }
        }
    }
    int imin = min(i1, i2), imax = max(i1, i2);
    lkeys[b * 8192 + t] = (i1 != i2) ? (imin * 300 + imax) : BIGK;
}

// Dedup sorted keys -> line segments + mask.
__global__ void finalize_kernel(const int* __restrict__ lkeys,
                                const float* __restrict__ junc,
                                float* __restrict__ out) {
    const int b = blockIdx.y;
    const int t = blockIdx.x * 256 + threadIdx.x;
    if (t >= 5000) return;
    const int* lk = lkeys + b * 8192;
    int sk = lk[t];
    bool first = ((t == 0) || (sk != lk[t - 1])) && (sk < BIGK);
    int a  = first ? sk / 300 : 0;
    int bb = first ? sk % 300 : 0;
    float p0x = junc[(size_t)(b * 300 + a) * 2];
    float p0y = junc[(size_t)(b * 300 + a) * 2 + 1];
    float p1x = junc[(size_t)(b * 300 + bb) * 2];
    float p1y = junc[(size_t)(b * 300 + bb) * 2 + 1];
    if (p0y > p1y) {
        float tx = p0x; p0x = p1x; p1x = tx;
        float ty = p0y; p0y = p1y; p1y = ty;
    }
    size_t base = OFF_LOI + (size_t)(b * 5000 + t) * 4;
    out[base]     = p0x;
    out[base + 1] = p0y;
    out[base + 2] = p1x;
    out[base + 3] = p1y;
    out[OFF_MASK + b * 5000 + t] = first ? 1.0f : 0.0f;
}

extern "C" void kernel_launch(void* const* d_in, const int* in_sizes, int n_in,
                              void* d_out, int out_size, void* d_ws, size_t ws_size,
                              hipStream_t stream) {
    const float* feat  = (const float*)d_in[0];
    const float* w1    = (const float*)d_in[1];
    const float* b1    = (const float*)d_in[2];
    const float* gamma = (const float*)d_in[3];
    const float* beta  = (const float*)d_in[4];
    const float* mean  = (const float*)d_in[5];
    const float* var   = (const float*)d_in[6];
    const float* w2    = (const float*)d_in[7];
    const float* b2    = (const float*)d_in[8];
    float* out = (float*)d_out;
    char*  ws  = (char*)d_ws;

    if (ws_size < WS_NEED) return;   // ~159.6 MB needed

    float* y1 = (float*)(ws + WS_Y1);
    unsigned long long* jsort = (unsigned long long*)(ws + WS_JSORT);
    unsigned long long* csort = (unsigned long long*)(ws + WS_CSORT);
    float* junc = (float*)(ws + WS_JUNC);
    int* jvalid = (int*)(ws + WS_JVAL);
    int* lkeys  = (int*)(ws + WS_LKEY);

    // 1. conv1 + BN + ReLU -> y1
    conv1_kernel<<<dim3(10, 10, NB * 12), dim3(16, 16), 0, stream>>>(
        feat, w1, b1, gamma, beta, mean, var, y1);

    // 2. conv2 (grouped, SEL channels only) -> maps in d_out
    conv2_kernel<<<dim3(10, 10, NB * 6), dim3(16, 16), 0, stream>>>(y1, w2, b2, out);

    // 3. NMS + pack sort keys
    nms_pack_kernel<<<dim3(NB * 100), dim3(256), 0, stream>>>(out, jsort, csort);

    // 4. sort both key sets (8 arrays: 4 jmap + 4 cmap, contiguous)
    sort64_desc_kernel<<<dim3(8), dim3(1024), 0, stream>>>(jsort);

    // 5. junctions
    junction_kernel<<<dim3(NB), dim3(320), 0, stream>>>(jsort, out, junc, jvalid);

    // 6. line keys
    lines_kernel<<<dim3(32, NB), dim3(256), 0, stream>>>(csort, junc, jvalid, out, lkeys);

    // 7. sort line keys ascending
    sort32_asc_kernel<<<dim3(NB), dim3(1024), 0, stream>>>(lkeys);

    // 8. dedup + emit loi/mask
    finalize_kernel<<<dim3(20, NB), dim3(256), 0, stream>>>(lkeys, junc, out);
}

// Round 2
// 4395.683 us; speedup vs baseline: 1.2676x; 1.2676x over previous
//
#include <hip/hip_runtime.h>
#include <math.h>

#define IMG   160
#define HWSZ  25600
#define NB    4
#define CIN   256
#define COUT1 384
#define BIGK  90000

// output offsets (in floats)
#define OFF_LMAP 0
#define OFF_JMAP 102400
#define OFF_JOFF 204800
#define OFF_CMAP 409600
#define OFF_COFF 512000
#define OFF_LVEC 716800
#define OFF_LOI  1126400
#define OFF_MASK 1206400

// workspace offsets (bytes)
static const size_t WS_Y1    = 0;
static const size_t WS_JSORT = (size_t)NB * COUT1 * HWSZ * 4;            // 157286400
static const size_t WS_CSORT = WS_JSORT + (size_t)NB * 32768 * 8;
static const size_t WS_JUNC  = WS_CSORT + (size_t)NB * 32768 * 8;
static const size_t WS_JVAL  = WS_JUNC + (size_t)NB * 300 * 2 * 4;
static const size_t WS_LKEY  = WS_JVAL + (size_t)NB * 300 * 4;
static const size_t WS_NEED  = WS_LKEY + (size_t)NB * 8192 * 4;

typedef unsigned long long u64;

__device__ __forceinline__ float clip_coord(float v) {
    return fminf(fmaxf(v, 0.0f), 159.9999f);
}

__device__ __forceinline__ float sigmoidf(float v) {
    return 1.0f / (1.0f + expf(-v));
}

// ---------------------------------------------------------------------------
// conv1 (3x3, 256->384) + BN + ReLU.  Block = 16x16 pixels, 32 output chans.
// 4 input channels staged in LDS per barrier round; weights via scalar loads
// with constant immediate offsets (wb[o*2304+j]).
// __launch_bounds__(256,2): cap 256 VGPR -> acc[32] stays in registers.
// ---------------------------------------------------------------------------
__global__ __launch_bounds__(256, 2) void conv1_kernel(
    const float* __restrict__ feat, const float* __restrict__ w1,
    const float* __restrict__ b1, const float* __restrict__ gamma,
    const float* __restrict__ beta, const float* __restrict__ mean,
    const float* __restrict__ var, float* __restrict__ y1) {
    const int bz  = blockIdx.z;
    const int b   = bz / 12;
    const int oc0 = (bz % 12) * 32;
    const int tx  = blockIdx.x * 16, ty = blockIdx.y * 16;
    const int lx  = threadIdx.x, ly = threadIdx.y;
    const int tid = ly * 16 + lx;

    __shared__ float tin[4][18][33];   // stride 33: bank = (row+col)%32, <=4-way
    float acc[32];
#pragma unroll
    for (int o = 0; o < 32; ++o) acc[o] = 0.0f;

    const float* fb = feat + (size_t)b * CIN * HWSZ;

    for (int ic0 = 0; ic0 < CIN; ic0 += 4) {
        for (int i = tid; i < 1296; i += 256) {
            int c = i / 324, rem = i - c * 324;
            int r = rem / 18, col = rem - r * 18;
            int gy = ty - 1 + r, gx = tx - 1 + col;
            float v = 0.0f;
            if (gy >= 0 && gy < IMG && gx >= 0 && gx < IMG)
                v = fb[(size_t)(ic0 + c) * HWSZ + gy * IMG + gx];
            tin[c][r][col] = v;
        }
        __syncthreads();
#pragma unroll
        for (int c = 0; c < 4; ++c) {
            float n0 = tin[c][ly][lx],     n1 = tin[c][ly][lx + 1],     n2 = tin[c][ly][lx + 2];
            float n3 = tin[c][ly + 1][lx], n4 = tin[c][ly + 1][lx + 1], n5 = tin[c][ly + 1][lx + 2];
            float n6 = tin[c][ly + 2][lx], n7 = tin[c][ly + 2][lx + 1], n8 = tin[c][ly + 2][lx + 2];
            const float* wb = w1 + ((size_t)oc0 * CIN + (ic0 + c)) * 9;
#pragma unroll
            for (int o = 0; o < 32; ++o) {
                const float* wp = wb + o * (CIN * 9);
                acc[o] = fmaf(n0, wp[0], fmaf(n1, wp[1], fmaf(n2, wp[2],
                         fmaf(n3, wp[3], fmaf(n4, wp[4], fmaf(n5, wp[5],
                         fmaf(n6, wp[6], fmaf(n7, wp[7], fmaf(n8, wp[8], acc[o])))))))));
            }
        }
        __syncthreads();
    }

    const int oy = ty + ly, ox = tx + lx;
#pragma unroll
    for (int o = 0; o < 32; ++o) {
        int oc  = oc0 + o;
        float v = acc[o] + b1[oc];
        v = (v - mean[oc]) * (gamma[oc] / sqrtf(var[oc] + 1e-5f)) + beta[oc];
        v = fmaxf(v, 0.0f);
        y1[((size_t)(b * COUT1 + oc)) * HWSZ + oy * IMG + ox] = v;
    }
}

// ---------------------------------------------------------------------------
// conv2: grouped 3x3, only the SEL channels; sigmoid where needed; -> d_out.
// Same 4-channel LDS chunking.
// ---------------------------------------------------------------------------
__global__ __launch_bounds__(256, 2) void conv2_kernel(
    const float* __restrict__ y1, const float* __restrict__ w2,
    const float* __restrict__ b2, float* __restrict__ out) {
    const int KH[6]   = {1, 1, 2, 1, 2, 4};
    const int REG[6]  = {OFF_LMAP, OFF_JMAP, OFF_JOFF, OFF_CMAP, OFF_COFF, OFF_LVEC};
    const int SIGF[6] = {1, 1, 0, 1, 0, 0};

    const int bz = blockIdx.z;
    const int b  = bz / 6;
    const int h  = bz % 6;
    const int k  = KH[h];
    const int tx = blockIdx.x * 16, ty = blockIdx.y * 16;
    const int lx = threadIdx.x, ly = threadIdx.y;
    const int tid = ly * 16 + lx;

    __shared__ float tin[4][18][33];
    float acc[4] = {0.0f, 0.0f, 0.0f, 0.0f};

    const float* yb = y1 + ((size_t)(b * COUT1 + h * 64)) * HWSZ;

    for (int ic0 = 0; ic0 < 64; ic0 += 4) {
        for (int i = tid; i < 1296; i += 256) {
            int c = i / 324, rem = i - c * 324;
            int r = rem / 18, col = rem - r * 18;
            int gy = ty - 1 + r, gx = tx - 1 + col;
            float v = 0.0f;
            if (gy >= 0 && gy < IMG && gx >= 0 && gx < IMG)
                v = yb[(size_t)(ic0 + c) * HWSZ + gy * IMG + gx];
            tin[c][r][col] = v;
        }
        __syncthreads();
#pragma unroll
        for (int c = 0; c < 4; ++c) {
            float n0 = tin[c][ly][lx],     n1 = tin[c][ly][lx + 1],     n2 = tin[c][ly][lx + 2];
            float n3 = tin[c][ly + 1][lx], n4 = tin[c][ly + 1][lx + 1], n5 = tin[c][ly + 1][lx + 2];
            float n6 = tin[c][ly + 2][lx], n7 = tin[c][ly + 2][lx + 1], n8 = tin[c][ly + 2][lx + 2];
#pragma unroll
            for (int o = 0; o < 4; ++o) {
                if (o < k) {
                    const float* wp = w2 + ((size_t)((h * 4 + o) * 64 + (ic0 + c))) * 9;
                    acc[o] = fmaf(n0, wp[0], fmaf(n1, wp[1], fmaf(n2, wp[2],
                             fmaf(n3, wp[3], fmaf(n4, wp[4], fmaf(n5, wp[5],
                             fmaf(n6, wp[6], fmaf(n7, wp[7], fmaf(n8, wp[8], acc[o])))))))));
                }
            }
        }
        __syncthreads();
    }

    const int p = (ty + ly) * IMG + tx + lx;
    for (int o = 0; o < k; ++o) {
        float v = acc[o] + b2[h * 4 + o];
        if (SIGF[h]) v = sigmoidf(v);
        out[REG[h] + ((size_t)(b * k + o)) * HWSZ + p] = v;
    }
}

// ---------------------------------------------------------------------------
// NMS on jmap + pack sort keys (value_bits<<32 | ~index  == lax.top_k order).
// ---------------------------------------------------------------------------
__global__ void nms_pack_kernel(const float* __restrict__ out,
                                u64* __restrict__ jsort,
                                u64* __restrict__ csort) {
    const int g = blockIdx.x;           // 0..399
    const int b = g / 100, q = g % 100;
    const int p = q * 256 + threadIdx.x;
    const float* jm = out + OFF_JMAP + (size_t)b * HWSZ;
    const float* cm = out + OFF_CMAP + (size_t)b * HWSZ;

    const int x = p % IMG, y = p / IMG;
    float v = jm[p];
    float mx = v;
#pragma unroll
    for (int dy = -1; dy <= 1; ++dy)
#pragma unroll
        for (int dx = -1; dx <= 1; ++dx) {
            int nx = x + dx, ny = y + dy;
            if (nx >= 0 && nx < IMG && ny >= 0 && ny < IMG)
                mx = fmaxf(mx, jm[ny * IMG + nx]);
        }
    float nmsv = (v == mx) ? v : 0.0f;

    u64 tagj = ((u64)__float_as_uint(nmsv) << 32)
             | (u64)(0xFFFFFFFFu - (unsigned)p);
    u64 tagc = ((u64)__float_as_uint(cm[p]) << 32)
             | (u64)(0xFFFFFFFFu - (unsigned)p);
    jsort[(size_t)b * 32768 + p] = tagj;
    csort[(size_t)b * 32768 + p] = tagc;
    if (q < 28) {                        // pad 25600..32767 with minimal keys
        int pp = 25600 + q * 256 + threadIdx.x;
        jsort[(size_t)b * 32768 + pp] = 0ull;
        csort[(size_t)b * 32768 + pp] = 0ull;
    }
}

// ---------------------------------------------------------------------------
// Hybrid bitonic sort, descending, 8 arrays x 32768 u64.
// Phase A (LDS): all stages k=2..8192 within each 8192-chunk.
// Global steps: (k=16384,j=8192), (k=32768,j=16384), (k=32768,j=8192).
// Phase B (LDS): j<=4096 tail of k=16384 and k=32768.
// Identical comparison network to a monolithic bitonic sort.
// ---------------------------------------------------------------------------
__global__ __launch_bounds__(1024) void sort64_ldsA(u64* __restrict__ buf) {
    __shared__ u64 s[8192];
    const size_t base = (size_t)blockIdx.x * 8192;   // 32 chunks (8 arrays x 4)
    const int cbase = (blockIdx.x & 3) * 8192;       // chunk offset within array
    for (int i = threadIdx.x; i < 8192; i += 1024) s[i] = buf[base + i];
    for (int k = 2; k <= 8192; k <<= 1)
        for (int j = k >> 1; j > 0; j >>= 1) {
            __syncthreads();
            for (int t = threadIdx.x; t < 4096; t += 1024) {
                int i = ((t & ~(j - 1)) << 1) | (t & (j - 1));
                int l = i | j;
                bool desc = (((i + cbase) & k) == 0);
                u64 x = s[i], y = s[l];
                if (desc ? (x < y) : (x > y)) { s[i] = y; s[l] = x; }
            }
        }
    __syncthreads();
    for (int i = threadIdx.x; i < 8192; i += 1024) buf[base + i] = s[i];
}

__global__ void sort64_gstep(u64* __restrict__ buf, int k, int j) {
    int t = blockIdx.x * 256 + threadIdx.x;          // 8 arrays * 16384 pairs
    int arr = t >> 14, p = t & 16383;
    int i = ((p & ~(j - 1)) << 1) | (p & (j - 1));
    int l = i | j;
    bool desc = ((i & k) == 0);
    u64* a = buf + (size_t)arr * 32768;
    u64 x = a[i], y = a[l];
    if (desc ? (x < y) : (x > y)) { a[i] = y; a[l] = x; }
}

__global__ __launch_bounds__(1024) void sort64_ldsB(u64* __restrict__ buf, int k) {
    __shared__ u64 s[8192];
    const size_t base = (size_t)blockIdx.x * 8192;
    const int cbase = (blockIdx.x & 3) * 8192;
    for (int i = threadIdx.x; i < 8192; i += 1024) s[i] = buf[base + i];
    for (int j = 4096; j > 0; j >>= 1) {
        __syncthreads();
        for (int t = threadIdx.x; t < 4096; t += 1024) {
            int i = ((t & ~(j - 1)) << 1) | (t & (j - 1));
            int l = i | j;
            bool desc = (((i + cbase) & k) == 0);
            u64 x = s[i], y = s[l];
            if (desc ? (x < y) : (x > y)) { s[i] = y; s[l] = x; }
        }
    }
    __syncthreads();
    for (int i = threadIdx.x; i < 8192; i += 1024) buf[base + i] = s[i];
}

// Full-LDS bitonic sort, ascending, 8192 int keys (one array per block).
__global__ __launch_bounds__(1024) void sort32_lds(int* __restrict__ buf) {
    __shared__ int s[8192];
    int* a = buf + (size_t)blockIdx.x * 8192;
    for (int i = threadIdx.x; i < 8192; i += 1024) s[i] = a[i];
    for (int k = 2; k <= 8192; k <<= 1)
        for (int j = k >> 1; j > 0; j >>= 1) {
            __syncthreads();
            for (int t = threadIdx.x; t < 4096; t += 1024) {
                int i = ((t & ~(j - 1)) << 1) | (t & (j - 1));
                int l = i | j;
                bool asc = ((i & k) == 0);
                int x = s[i], y = s[l];
                if (asc ? (x > y) : (x < y)) { s[i] = y; s[l] = x; }
            }
        }
    __syncthreads();
    for (int i = threadIdx.x; i < 8192; i += 1024) a[i] = s[i];
}

// Top-300 junctions: coordinates + validity.
__global__ void junction_kernel(const u64* __restrict__ jsort,
                                const float* __restrict__ out,
                                float* __restrict__ junc, int* __restrict__ jvalid) {
    const int b = blockIdx.x;
    const int t = threadIdx.x;
    if (t >= 300) return;
    u64 key = jsort[(size_t)b * 32768 + t];
    float score  = __uint_as_float((unsigned)(key >> 32));
    unsigned idx = 0xFFFFFFFFu - (unsigned)(key & 0xFFFFFFFFull);
    const float* j0 = out + OFF_JOFF + (size_t)(b * 2) * HWSZ;
    const float* j1 = j0 + HWSZ;
    float jx = (float)(idx % IMG) + j0[idx] + 0.5f;
    float jy = (float)(idx / IMG) + j1[idx] + 0.5f;
    junc[(size_t)(b * 300 + t) * 2]     = clip_coord(jx);
    junc[(size_t)(b * 300 + t) * 2 + 1] = clip_coord(jy);
    jvalid[b * 300 + t] = (score >= 0.008f) ? 1 : 0;
}

// Top-5000 centers -> line endpoints -> nearest-junction keys.
__global__ void lines_kernel(const u64* __restrict__ csort,
                             const float* __restrict__ junc,
                             const int* __restrict__ jvalid,
                             const float* __restrict__ out,
                             int* __restrict__ lkeys) {
    const int b = blockIdx.y;
    const int t = blockIdx.x * 256 + threadIdx.x;

    __shared__ float jx[300], jy[300];
    __shared__ int jv[300];
    for (int i = threadIdx.x; i < 300; i += 256) {
        jx[i] = junc[(size_t)(b * 300 + i) * 2];
        jy[i] = junc[(size_t)(b * 300 + i) * 2 + 1];
        jv[i] = jvalid[b * 300 + i];
    }
    __syncthreads();

    if (t >= 8192) return;
    if (t >= 5000) { lkeys[b * 8192 + t] = 0x7FFFFFFF; return; }

    u64 key = csort[(size_t)b * 32768 + t];
    unsigned idx = 0xFFFFFFFFu - (unsigned)(key & 0xFFFFFFFFull);
    const float* c0 = out + OFF_COFF + (size_t)(b * 2) * HWSZ;
    const float* c1 = c0 + HWSZ;
    const float* lv = out + OFF_LVEC + (size_t)(b * 4) * HWSZ;

    float cx = (float)(idx % IMG) + c0[idx] + 0.5f;
    float cy = (float)(idx / IMG) + c1[idx] + 0.5f;
    float e0x = clip_coord(cx + lv[idx]);
    float e0y = clip_coord(cy + lv[HWSZ + idx]);
    float e1x = clip_coord(cx + lv[2 * HWSZ + idx]);
    float e1y = clip_coord(cy + lv[3 * HWSZ + idx]);

    float m1 = 1e18f, m2 = 1e18f;
    int i1 = 0, i2 = 0;
    for (int j = 0; j < 300; ++j) {
        if (jv[j]) {
            float dx = e0x - jx[j], dy = e0y - jy[j];
            float d = dx * dx + dy * dy;
            if (d < m1) { m1 = d; i1 = j; }
            dx = e1x - jx[j]; dy = e1y - jy[j];
            d = dx * dx + dy * dy;
            if (d < m2) { m2 = d; i2 = j; }
        }
    }
    int imin = min(i1, i2), imax = max(i1, i2);
    lkeys[b * 8192 + t] = (i1 != i2) ? (imin * 300 + imax) : BIGK;
}

// Dedup sorted keys -> line segments + mask.
__global__ void finalize_kernel(const int* __restrict__ lkeys,
                                const float* __restrict__ junc,
                                float* __restrict__ out) {
    const int b = blockIdx.y;
    const int t = blockIdx.x * 256 + threadIdx.x;
    if (t >= 5000) return;
    const int* lk = lkeys + b * 8192;
    int sk = lk[t];
    bool first = ((t == 0) || (sk != lk[t - 1])) && (sk < BIGK);
    int a  = first ? sk / 300 : 0;
    int bb = first ? sk % 300 : 0;
    float p0x = junc[(size_t)(b * 300 + a) * 2];
    float p0y = junc[(size_t)(b * 300 + a) * 2 + 1];
    float p1x = junc[(size_t)(b * 300 + bb) * 2];
    float p1y = junc[(size_t)(b * 300 + bb) * 2 + 1];
    if (p0y > p1y) {
        float tx = p0x; p0x = p1x; p1x = tx;
        float ty = p0y; p0y = p1y; p1y = ty;
    }
    size_t base = OFF_LOI + (size_t)(b * 5000 + t) * 4;
    out[base]     = p0x;
    out[base + 1] = p0y;
    out[base + 2] = p1x;
    out[base + 3] = p1y;
    out[OFF_MASK + b * 5000 + t] = first ? 1.0f : 0.0f;
}

extern "C" void kernel_launch(void* const* d_in, const int* in_sizes, int n_in,
                              void* d_out, int out_size, void* d_ws, size_t ws_size,
                              hipStream_t stream) {
    const float* feat  = (const float*)d_in[0];
    const float* w1    = (const float*)d_in[1];
    const float* b1    = (const float*)d_in[2];
    const float* gamma = (const float*)d_in[3];
    const float* beta  = (const float*)d_in[4];
    const float* mean  = (const float*)d_in[5];
    const float* var   = (const float*)d_in[6];
    const float* w2    = (const float*)d_in[7];
    const float* b2    = (const float*)d_in[8];
    float* out = (float*)d_out;
    char*  ws  = (char*)d_ws;

    if (ws_size < WS_NEED) return;   // ~159.6 MB needed

    float* y1 = (float*)(ws + WS_Y1);
    u64* jsort = (u64*)(ws + WS_JSORT);
    float* junc = (float*)(ws + WS_JUNC);
    int* jvalid = (int*)(ws + WS_JVAL);
    int* lkeys  = (int*)(ws + WS_LKEY);
    u64* csort = (u64*)(ws + WS_CSORT);

    // 1. conv1 + BN + ReLU -> y1
    conv1_kernel<<<dim3(10, 10, NB * 12), dim3(16, 16), 0, stream>>>(
        feat, w1, b1, gamma, beta, mean, var, y1);

    // 2. conv2 (grouped, SEL channels only) -> maps in d_out
    conv2_kernel<<<dim3(10, 10, NB * 6), dim3(16, 16), 0, stream>>>(y1, w2, b2, out);

    // 3. NMS + pack sort keys
    nms_pack_kernel<<<dim3(NB * 100), dim3(256), 0, stream>>>(out, jsort, csort);

    // 4. hybrid bitonic sort of 8 u64 arrays (4 jmap + 4 cmap, contiguous)
    sort64_ldsA<<<dim3(32), dim3(1024), 0, stream>>>(jsort);
    sort64_gstep<<<dim3(512), dim3(256), 0, stream>>>(jsort, 16384, 8192);
    sort64_ldsB<<<dim3(32), dim3(1024), 0, stream>>>(jsort, 16384);
    sort64_gstep<<<dim3(512), dim3(256), 0, stream>>>(jsort, 32768, 16384);
    sort64_gstep<<<dim3(512), dim3(256), 0, stream>>>(jsort, 32768, 8192);
    sort64_ldsB<<<dim3(32), dim3(1024), 0, stream>>>(jsort, 32768);

    // 5. junctions
    junction_kernel<<<dim3(NB), dim3(320), 0, stream>>>(jsort, out, junc, jvalid);

    // 6. line keys
    lines_kernel<<<dim3(32, NB), dim3(256), 0, stream>>>(csort, junc, jvalid, out, lkeys);

    // 7. sort line keys ascending (full LDS)
    sort32_lds<<<dim3(NB), dim3(1024), 0, stream>>>(lkeys);

    // 8. dedup + emit loi/mask
    finalize_kernel<<<dim3(20, NB), dim3(256), 0, stream>>>(lkeys, junc, out);
}

// Round 3
// 4261.266 us; speedup vs baseline: 1.3076x; 1.0315x over previous
//
#include <hip/hip_runtime.h>
#include <math.h>

#define IMG   160
#define HWSZ  25600
#define NB    4
#define CIN   256
#define COUT1 384
#define BIGK  90000

// output offsets (in floats)
#define OFF_LMAP 0
#define OFF_JMAP 102400
#define OFF_JOFF 204800
#define OFF_CMAP 409600
#define OFF_COFF 512000
#define OFF_LVEC 716800
#define OFF_LOI  1126400
#define OFF_MASK 1206400

// workspace offsets (bytes)
static const size_t WS_Y1    = 0;
static const size_t WS_JSORT = (size_t)NB * COUT1 * HWSZ * 4;            // 157286400
static const size_t WS_CSORT = WS_JSORT + (size_t)NB * 32768 * 8;
static const size_t WS_JUNC  = WS_CSORT + (size_t)NB * 32768 * 8;
static const size_t WS_JVAL  = WS_JUNC + (size_t)NB * 300 * 2 * 4;
static const size_t WS_LKEY  = WS_JVAL + (size_t)NB * 300 * 4;
static const size_t WS_NEED  = WS_LKEY + (size_t)NB * 8192 * 4;

typedef unsigned long long u64;

__device__ __forceinline__ float clip_coord(float v) {
    return fminf(fmaxf(v, 0.0f), 159.9999f);
}

__device__ __forceinline__ float sigmoidf(float v) {
    return 1.0f / (1.0f + expf(-v));
}

// ---------------------------------------------------------------------------
// conv1 (3x3, 256->384) + BN + ReLU.
// Register tiling: each thread computes 4 pixels x 8 output channels.
//   wave (tid/64) = oc-group  -> weight addresses wave-uniform (scalar loads)
//   lane: row = lane/4 (16 rows), cg = lane%4 (4-pixel column group)
// Per ic: 72 scalar weight loads : 288 FMAs (4:1) -- VALU-bound.
// FMA chain order (tap 8 -> tap 0, ic ascending) matches the previous
// rounds' fmaf nesting exactly -> conv output bitwise identical.
// ---------------------------------------------------------------------------
__global__ __launch_bounds__(256, 2) void conv1_kernel(
    const float* __restrict__ feat, const float* __restrict__ w1,
    const float* __restrict__ b1, const float* __restrict__ gamma,
    const float* __restrict__ beta, const float* __restrict__ mean,
    const float* __restrict__ var, float* __restrict__ y1) {
    const int bz  = blockIdx.z;
    const int b   = bz / 12;
    const int oc0 = (bz % 12) * 32;
    const int tx  = blockIdx.x * 16, ty = blockIdx.y * 16;
    const int tid  = threadIdx.x;
    const int og   = __builtin_amdgcn_readfirstlane(tid >> 6);  // wave idx 0..3
    const int lane = tid & 63;
    const int row  = lane >> 2;        // 0..15
    const int cg   = lane & 3;         // 0..3 -> pixels cg*4 .. cg*4+3

    __shared__ float tin[4][18][35];   // stride 35: (3r+c)%32 -> max 2-way (free)
    float acc[8][4];
#pragma unroll
    for (int o = 0; o < 8; ++o)
#pragma unroll
        for (int p = 0; p < 4; ++p) acc[o][p] = 0.0f;

    const float* fb = feat + (size_t)b * CIN * HWSZ;

    for (int ic0 = 0; ic0 < CIN; ic0 += 4) {
#pragma unroll
        for (int ii = 0; ii < 6; ++ii) {
            int i = tid + ii * 256;
            if (i < 1296) {
                int c = i / 324, rem = i - c * 324;
                int r = rem / 18, col = rem - r * 18;
                int gy = ty - 1 + r, gx = tx - 1 + col;
                float v = 0.0f;
                if (gy >= 0 && gy < IMG && gx >= 0 && gx < IMG)
                    v = fb[(size_t)(ic0 + c) * HWSZ + gy * IMG + gx];
                tin[c][r][col] = v;
            }
        }
        __syncthreads();
#pragma unroll
        for (int c = 0; c < 4; ++c) {
            const int ic = ic0 + c;
            float px[3][6];
#pragma unroll
            for (int ky = 0; ky < 3; ++ky)
#pragma unroll
                for (int i = 0; i < 6; ++i)
                    px[ky][i] = tin[c][row + ky][cg * 4 + i];
#pragma unroll
            for (int o = 0; o < 8; ++o) {
                const float* wp = w1 + ((size_t)(oc0 + og * 8 + o) * CIN + ic) * 9;
                float w[9];
#pragma unroll
                for (int t = 0; t < 9; ++t) w[t] = wp[t];
#pragma unroll
                for (int p = 0; p < 4; ++p) {
#pragma unroll
                    for (int t = 8; t >= 0; --t)   // tap8 -> tap0: matches old nesting
                        acc[o][p] = fmaf(px[t / 3][t % 3 + p], w[t], acc[o][p]);
                }
            }
        }
        __syncthreads();
    }

    const int oy = ty + row;
#pragma unroll
    for (int o = 0; o < 8; ++o) {
        const int oc = oc0 + og * 8 + o;
        const float bn_s = gamma[oc] / sqrtf(var[oc] + 1e-5f);
        const float bias = b1[oc], mu = mean[oc], bt = beta[oc];
        float* dst = y1 + ((size_t)(b * COUT1 + oc)) * HWSZ + oy * IMG + tx + cg * 4;
#pragma unroll
        for (int p = 0; p < 4; ++p) {
            float v = acc[o][p] + bias;
            v = (v - mu) * bn_s + bt;
            dst[p] = fmaxf(v, 0.0f);
        }
    }
}

// ---------------------------------------------------------------------------
// conv2: grouped 3x3, only the SEL channels; sigmoid where needed; -> d_out.
// (unchanged from round 2 -- within the 190us tail)
// ---------------------------------------------------------------------------
__global__ __launch_bounds__(256, 2) void conv2_kernel(
    const float* __restrict__ y1, const float* __restrict__ w2,
    const float* __restrict__ b2, float* __restrict__ out) {
    const int KH[6]   = {1, 1, 2, 1, 2, 4};
    const int REG[6]  = {OFF_LMAP, OFF_JMAP, OFF_JOFF, OFF_CMAP, OFF_COFF, OFF_LVEC};
    const int SIGF[6] = {1, 1, 0, 1, 0, 0};

    const int bz = blockIdx.z;
    const int b  = bz / 6;
    const int h  = bz % 6;
    const int k  = KH[h];
    const int tx = blockIdx.x * 16, ty = blockIdx.y * 16;
    const int lx = threadIdx.x, ly = threadIdx.y;
    const int tid = ly * 16 + lx;

    __shared__ float tin[4][18][33];
    float acc[4] = {0.0f, 0.0f, 0.0f, 0.0f};

    const float* yb = y1 + ((size_t)(b * COUT1 + h * 64)) * HWSZ;

    for (int ic0 = 0; ic0 < 64; ic0 += 4) {
        for (int i = tid; i < 1296; i += 256) {
            int c = i / 324, rem = i - c * 324;
            int r = rem / 18, col = rem - r * 18;
            int gy = ty - 1 + r, gx = tx - 1 + col;
            float v = 0.0f;
            if (gy >= 0 && gy < IMG && gx >= 0 && gx < IMG)
                v = yb[(size_t)(ic0 + c) * HWSZ + gy * IMG + gx];
            tin[c][r][col] = v;
        }
        __syncthreads();
#pragma unroll
        for (int c = 0; c < 4; ++c) {
            float n0 = tin[c][ly][lx],     n1 = tin[c][ly][lx + 1],     n2 = tin[c][ly][lx + 2];
            float n3 = tin[c][ly + 1][lx], n4 = tin[c][ly + 1][lx + 1], n5 = tin[c][ly + 1][lx + 2];
            float n6 = tin[c][ly + 2][lx], n7 = tin[c][ly + 2][lx + 1], n8 = tin[c][ly + 2][lx + 2];
#pragma unroll
            for (int o = 0; o < 4; ++o) {
                if (o < k) {
                    const float* wp = w2 + ((size_t)((h * 4 + o) * 64 + (ic0 + c))) * 9;
                    acc[o] = fmaf(n0, wp[0], fmaf(n1, wp[1], fmaf(n2, wp[2],
                             fmaf(n3, wp[3], fmaf(n4, wp[4], fmaf(n5, wp[5],
                             fmaf(n6, wp[6], fmaf(n7, wp[7], fmaf(n8, wp[8], acc[o])))))))));
                }
            }
        }
        __syncthreads();
    }

    const int p = (ty + ly) * IMG + tx + lx;
    for (int o = 0; o < k; ++o) {
        float v = acc[o] + b2[h * 4 + o];
        if (SIGF[h]) v = sigmoidf(v);
        out[REG[h] + ((size_t)(b * k + o)) * HWSZ + p] = v;
    }
}

// ---------------------------------------------------------------------------
// NMS on jmap + pack sort keys (value_bits<<32 | ~index  == lax.top_k order).
// ---------------------------------------------------------------------------
__global__ void nms_pack_kernel(const float* __restrict__ out,
                                u64* __restrict__ jsort,
                                u64* __restrict__ csort) {
    const int g = blockIdx.x;           // 0..399
    const int b = g / 100, q = g % 100;
    const int p = q * 256 + threadIdx.x;
    const float* jm = out + OFF_JMAP + (size_t)b * HWSZ;
    const float* cm = out + OFF_CMAP + (size_t)b * HWSZ;

    const int x = p % IMG, y = p / IMG;
    float v = jm[p];
    float mx = v;
#pragma unroll
    for (int dy = -1; dy <= 1; ++dy)
#pragma unroll
        for (int dx = -1; dx <= 1; ++dx) {
            int nx = x + dx, ny = y + dy;
            if (nx >= 0 && nx < IMG && ny >= 0 && ny < IMG)
                mx = fmaxf(mx, jm[ny * IMG + nx]);
        }
    float nmsv = (v == mx) ? v : 0.0f;

    u64 tagj = ((u64)__float_as_uint(nmsv) << 32)
             | (u64)(0xFFFFFFFFu - (unsigned)p);
    u64 tagc = ((u64)__float_as_uint(cm[p]) << 32)
             | (u64)(0xFFFFFFFFu - (unsigned)p);
    jsort[(size_t)b * 32768 + p] = tagj;
    csort[(size_t)b * 32768 + p] = tagc;
    if (q < 28) {                        // pad 25600..32767 with minimal keys
        int pp = 25600 + q * 256 + threadIdx.x;
        jsort[(size_t)b * 32768 + pp] = 0ull;
        csort[(size_t)b * 32768 + pp] = 0ull;
    }
}

// ---------------------------------------------------------------------------
// Hybrid bitonic sort, descending, 8 arrays x 32768 u64.
// ---------------------------------------------------------------------------
__global__ __launch_bounds__(1024) void sort64_ldsA(u64* __restrict__ buf) {
    __shared__ u64 s[8192];
    const size_t base = (size_t)blockIdx.x * 8192;   // 32 chunks (8 arrays x 4)
    const int cbase = (blockIdx.x & 3) * 8192;       // chunk offset within array
    for (int i = threadIdx.x; i < 8192; i += 1024) s[i] = buf[base + i];
    for (int k = 2; k <= 8192; k <<= 1)
        for (int j = k >> 1; j > 0; j >>= 1) {
            __syncthreads();
            for (int t = threadIdx.x; t < 4096; t += 1024) {
                int i = ((t & ~(j - 1)) << 1) | (t & (j - 1));
                int l = i | j;
                bool desc = (((i + cbase) & k) == 0);
                u64 x = s[i], y = s[l];
                if (desc ? (x < y) : (x > y)) { s[i] = y; s[l] = x; }
            }
        }
    __syncthreads();
    for (int i = threadIdx.x; i < 8192; i += 1024) buf[base + i] = s[i];
}

__global__ void sort64_gstep(u64* __restrict__ buf, int k, int j) {
    int t = blockIdx.x * 256 + threadIdx.x;          // 8 arrays * 16384 pairs
    int arr = t >> 14, p = t & 16383;
    int i = ((p & ~(j - 1)) << 1) | (p & (j - 1));
    int l = i | j;
    bool desc = ((i & k) == 0);
    u64* a = buf + (size_t)arr * 32768;
    u64 x = a[i], y = a[l];
    if (desc ? (x < y) : (x > y)) { a[i] = y; a[l] = x; }
}

__global__ __launch_bounds__(1024) void sort64_ldsB(u64* __restrict__ buf, int k) {
    __shared__ u64 s[8192];
    const size_t base = (size_t)blockIdx.x * 8192;
    const int cbase = (blockIdx.x & 3) * 8192;
    for (int i = threadIdx.x; i < 8192; i += 1024) s[i] = buf[base + i];
    for (int j = 4096; j > 0; j >>= 1) {
        __syncthreads();
        for (int t = threadIdx.x; t < 4096; t += 1024) {
            int i = ((t & ~(j - 1)) << 1) | (t & (j - 1));
            int l = i | j;
            bool desc = (((i + cbase) & k) == 0);
            u64 x = s[i], y = s[l];
            if (desc ? (x < y) : (x > y)) { s[i] = y; s[l] = x; }
        }
    }
    __syncthreads();
    for (int i = threadIdx.x; i < 8192; i += 1024) buf[base + i] = s[i];
}

// Full-LDS bitonic sort, ascending, 8192 int keys (one array per block).
__global__ __launch_bounds__(1024) void sort32_lds(int* __restrict__ buf) {
    __shared__ int s[8192];
    int* a = buf + (size_t)blockIdx.x * 8192;
    for (int i = threadIdx.x; i < 8192; i += 1024) s[i] = a[i];
    for (int k = 2; k <= 8192; k <<= 1)
        for (int j = k >> 1; j > 0; j >>= 1) {
            __syncthreads();
            for (int t = threadIdx.x; t < 4096; t += 1024) {
                int i = ((t & ~(j - 1)) << 1) | (t & (j - 1));
                int l = i | j;
                bool asc = ((i & k) == 0);
                int x = s[i], y = s[l];
                if (asc ? (x > y) : (x < y)) { s[i] = y; s[l] = x; }
            }
        }
    __syncthreads();
    for (int i = threadIdx.x; i < 8192; i += 1024) a[i] = s[i];
}

// Top-300 junctions: coordinates + validity.
__global__ void junction_kernel(const u64* __restrict__ jsort,
                                const float* __restrict__ out,
                                float* __restrict__ junc, int* __restrict__ jvalid) {
    const int b = blockIdx.x;
    const int t = threadIdx.x;
    if (t >= 300) return;
    u64 key = jsort[(size_t)b * 32768 + t];
    float score  = __uint_as_float((unsigned)(key >> 32));
    unsigned idx = 0xFFFFFFFFu - (unsigned)(key & 0xFFFFFFFFull);
    const float* j0 = out + OFF_JOFF + (size_t)(b * 2) * HWSZ;
    const float* j1 = j0 + HWSZ;
    float jx = (float)(idx % IMG) + j0[idx] + 0.5f;
    float jy = (float)(idx / IMG) + j1[idx] + 0.5f;
    junc[(size_t)(b * 300 + t) * 2]     = clip_coord(jx);
    junc[(size_t)(b * 300 + t) * 2 + 1] = clip_coord(jy);
    jvalid[b * 300 + t] = (score >= 0.008f) ? 1 : 0;
}

// Top-5000 centers -> line endpoints -> nearest-junction keys.
__global__ void lines_kernel(const u64* __restrict__ csort,
                             const float* __restrict__ junc,
                             const int* __restrict__ jvalid,
                             const float* __restrict__ out,
                             int* __restrict__ lkeys) {
    const int b = blockIdx.y;
    const int t = blockIdx.x * 256 + threadIdx.x;

    __shared__ float jx[300], jy[300];
    __shared__ int jv[300];
    for (int i = threadIdx.x; i < 300; i += 256) {
        jx[i] = junc[(size_t)(b * 300 + i) * 2];
        jy[i] = junc[(size_t)(b * 300 + i) * 2 + 1];
        jv[i] = jvalid[b * 300 + i];
    }
    __syncthreads();

    if (t >= 8192) return;
    if (t >= 5000) { lkeys[b * 8192 + t] = 0x7FFFFFFF; return; }

    u64 key = csort[(size_t)b * 32768 + t];
    unsigned idx = 0xFFFFFFFFu - (unsigned)(key & 0xFFFFFFFFull);
    const float* c0 = out + OFF_COFF + (size_t)(b * 2) * HWSZ;
    const float* c1 = c0 + HWSZ;
    const float* lv = out + OFF_LVEC + (size_t)(b * 4) * HWSZ;

    float cx = (float)(idx % IMG) + c0[idx] + 0.5f;
    float cy = (float)(idx / IMG) + c1[idx] + 0.5f;
    float e0x = clip_coord(cx + lv[idx]);
    float e0y = clip_coord(cy + lv[HWSZ + idx]);
    float e1x = clip_coord(cx + lv[2 * HWSZ + idx]);
    float e1y = clip_coord(cy + lv[3 * HWSZ + idx]);

    float m1 = 1e18f, m2 = 1e18f;
    int i1 = 0, i2 = 0;
    for (int j = 0; j < 300; ++j) {
        if (jv[j]) {
            float dx = e0x - jx[j], dy = e0y - jy[j];
            float d = dx * dx + dy * dy;
            if (d < m1) { m1 = d; i1 = j; }
            dx = e1x - jx[j]; dy = e1y - jy[j];
            d = dx * dx + dy * dy;
            if (d < m2) { m2 = d; i2 = j; }
        }
    }
    int imin = min(i1, i2), imax = max(i1, i2);
    lkeys[b * 8192 + t] = (i1 != i2) ? (imin * 300 + imax) : BIGK;
}

// Dedup sorted keys -> line segments + mask.
__global__ void finalize_kernel(const int* __restrict__ lkeys,
                                const float* __restrict__ junc,
                                float* __restrict__ out) {
    const int b = blockIdx.y;
    const int t = blockIdx.x * 256 + threadIdx.x;
    if (t >= 5000) return;
    const int* lk = lkeys + b * 8192;
    int sk = lk[t];
    bool first = ((t == 0) || (sk != lk[t - 1])) && (sk < BIGK);
    int a  = first ? sk / 300 : 0;
    int bb = first ? sk % 300 : 0;
    float p0x = junc[(size_t)(b * 300 + a) * 2];
    float p0y = junc[(size_t)(b * 300 + a) * 2 + 1];
    float p1x = junc[(size_t)(b * 300 + bb) * 2];
    float p1y = junc[(size_t)(b * 300 + bb) * 2 + 1];
    if (p0y > p1y) {
        float tx = p0x; p0x = p1x; p1x = tx;
        float ty = p0y; p0y = p1y; p1y = ty;
    }
    size_t base = OFF_LOI + (size_t)(b * 5000 + t) * 4;
    out[base]     = p0x;
    out[base + 1] = p0y;
    out[base + 2] = p1x;
    out[base + 3] = p1y;
    out[OFF_MASK + b * 5000 + t] = first ? 1.0f : 0.0f;
}

extern "C" void kernel_launch(void* const* d_in, const int* in_sizes, int n_in,
                              void* d_out, int out_size, void* d_ws, size_t ws_size,
                              hipStream_t stream) {
    const float* feat  = (const float*)d_in[0];
    const float* w1    = (const float*)d_in[1];
    const float* b1    = (const float*)d_in[2];
    const float* gamma = (const float*)d_in[3];
    const float* beta  = (const float*)d_in[4];
    const float* mean  = (const float*)d_in[5];
    const float* var   = (const float*)d_in[6];
    const float* w2    = (const float*)d_in[7];
    const float* b2    = (const float*)d_in[8];
    float* out = (float*)d_out;
    char*  ws  = (char*)d_ws;

    if (ws_size < WS_NEED) return;   // ~159.6 MB needed

    float* y1 = (float*)(ws + WS_Y1);
    u64* jsort = (u64*)(ws + WS_JSORT);
    float* junc = (float*)(ws + WS_JUNC);
    int* jvalid = (int*)(ws + WS_JVAL);
    int* lkeys  = (int*)(ws + WS_LKEY);
    u64* csort = (u64*)(ws + WS_CSORT);

    // 1. conv1 + BN + ReLU -> y1
    conv1_kernel<<<dim3(10, 10, NB * 12), dim3(256), 0, stream>>>(
        feat, w1, b1, gamma, beta, mean, var, y1);

    // 2. conv2 (grouped, SEL channels only) -> maps in d_out
    conv2_kernel<<<dim3(10, 10, NB * 6), dim3(16, 16), 0, stream>>>(y1, w2, b2, out);

    // 3. NMS + pack sort keys
    nms_pack_kernel<<<dim3(NB * 100), dim3(256), 0, stream>>>(out, jsort, csort);

    // 4. hybrid bitonic sort of 8 u64 arrays (4 jmap + 4 cmap, contiguous)
    sort64_ldsA<<<dim3(32), dim3(1024), 0, stream>>>(jsort);
    sort64_gstep<<<dim3(512), dim3(256), 0, stream>>>(jsort, 16384, 8192);
    sort64_ldsB<<<dim3(32), dim3(1024), 0, stream>>>(jsort, 16384);
    sort64_gstep<<<dim3(512), dim3(256), 0, stream>>>(jsort, 32768, 16384);
    sort64_gstep<<<dim3(512), dim3(256), 0, stream>>>(jsort, 32768, 8192);
    sort64_ldsB<<<dim3(32), dim3(1024), 0, stream>>>(jsort, 32768);

    // 5. junctions
    junction_kernel<<<dim3(NB), dim3(320), 0, stream>>>(jsort, out, junc, jvalid);

    // 6. line keys
    lines_kernel<<<dim3(32, NB), dim3(256), 0, stream>>>(csort, junc, jvalid, out, lkeys);

    // 7. sort line keys ascending (full LDS)
    sort32_lds<<<dim3(NB), dim3(1024), 0, stream>>>(lkeys);

    // 8. dedup + emit loi/mask
    finalize_kernel<<<dim3(20, NB), dim3(256), 0, stream>>>(lkeys, junc, out);
}

// Round 4
// 3162.935 us; speedup vs baseline: 1.7616x; 1.3473x over previous
//
#include <hip/hip_runtime.h>
#include <math.h>

#define IMG   160
#define HWSZ  25600
#define NB    4
#define CIN   256
#define COUT1 384
#define BIGK  90000

// output offsets (in floats)
#define OFF_LMAP 0
#define OFF_JMAP 102400
#define OFF_JOFF 204800
#define OFF_CMAP 409600
#define OFF_COFF 512000
#define OFF_LVEC 716800
#define OFF_LOI  1126400
#define OFF_MASK 1206400

// workspace offsets (bytes)
static const size_t WS_Y1    = 0;
static const size_t WS_JSORT = (size_t)NB * COUT1 * HWSZ * 4;            // 157286400
static const size_t WS_CSORT = WS_JSORT + (size_t)NB * 32768 * 8;
static const size_t WS_JUNC  = WS_CSORT + (size_t)NB * 32768 * 8;
static const size_t WS_JVAL  = WS_JUNC + (size_t)NB * 300 * 2 * 4;
static const size_t WS_LKEY  = WS_JVAL + (size_t)NB * 300 * 4;
static const size_t WS_NEED  = WS_LKEY + (size_t)NB * 8192 * 4;

typedef unsigned long long u64;

__device__ __forceinline__ float clip_coord(float v) {
    return fminf(fmaxf(v, 0.0f), 159.9999f);
}

__device__ __forceinline__ float sigmoidf(float v) {
    return 1.0f / (1.0f + expf(-v));
}

// ---------------------------------------------------------------------------
// conv1 (3x3, 256->384) + BN + ReLU.
// Tile: 16 rows x 32 cols x 32 oc per block (grid 5x10x48).
// Thread: 8 oc x 8 px.  ALL inner-loop data comes from LDS:
//   - input tile tin[8 ic][18][35]   (pixel reads, <=2-way banked = free)
//   - weights   wlds[8 ic][32*9]     (broadcast reads, conflict-free)
// Per (thread, ic): 576 FMA vs ~39 LDS reads -> >90% FMA issue density.
// FMA chain per accumulator: ic ascending, tap 8->0  == rounds 2/3 exactly
// -> conv output bitwise identical (keeps the passing top-k selections).
// ---------------------------------------------------------------------------
__global__ __launch_bounds__(256, 3) void conv1_kernel(
    const float* __restrict__ feat, const float* __restrict__ w1,
    const float* __restrict__ b1, const float* __restrict__ gamma,
    const float* __restrict__ beta, const float* __restrict__ mean,
    const float* __restrict__ var, float* __restrict__ y1) {
    const int bz  = blockIdx.z;
    const int b   = bz / 12;
    const int oc0 = (bz % 12) * 32;
    const int tx  = blockIdx.x * 32, ty = blockIdx.y * 16;
    const int tid  = threadIdx.x;
    const int og   = __builtin_amdgcn_readfirstlane(tid >> 6);  // wave idx 0..3
    const int lane = tid & 63;
    const int row  = lane >> 2;        // 0..15
    const int cg   = lane & 3;         // 0..3 -> pixels cg*8 .. cg*8+7

    __shared__ float tin[8][18][35];   // input tile + halo, stride 35
    __shared__ float wlds[8][288];     // [ic][o*9+t]

    float acc[8][8];
#pragma unroll
    for (int o = 0; o < 8; ++o)
#pragma unroll
        for (int p = 0; p < 8; ++p) acc[o][p] = 0.0f;

    const float* fb = feat + (size_t)b * CIN * HWSZ;

    for (int ic0 = 0; ic0 < CIN; ic0 += 8) {
        // stage input: 8 x 18 x 34 = 4896 floats
        for (int i = tid; i < 4896; i += 256) {
            int c = i / 612, rem = i - c * 612;
            int r = rem / 34, col = rem - r * 34;
            int gy = ty - 1 + r, gx = tx - 1 + col;
            float v = 0.0f;
            if (gy >= 0 && gy < IMG && gx >= 0 && gx < IMG)
                v = fb[(size_t)(ic0 + c) * HWSZ + gy * IMG + gx];
            tin[c][r][col] = v;
        }
        // stage weights: 32 oc x 72 consecutive floats (72 = 8 ic * 9 taps)
        for (int i = tid; i < 2304; i += 256) {
            int o = i / 72, rem = i - o * 72;       // rem = c*9 + t
            wlds[rem / 9][o * 9 + rem % 9] =
                w1[(size_t)(oc0 + o) * (CIN * 9) + (size_t)ic0 * 9 + rem];
        }
        __syncthreads();

#pragma unroll 1
        for (int c = 0; c < 8; ++c) {
            float px[3][10];
#pragma unroll
            for (int ky = 0; ky < 3; ++ky)
#pragma unroll
                for (int i = 0; i < 10; ++i)
                    px[ky][i] = tin[c][row + ky][cg * 8 + i];
#pragma unroll
            for (int o = 0; o < 8; ++o) {
                const float* wp = &wlds[c][(og * 8 + o) * 9];
                float w[9];
#pragma unroll
                for (int t = 0; t < 9; ++t) w[t] = wp[t];
#pragma unroll
                for (int p = 0; p < 8; ++p) {
#pragma unroll
                    for (int t = 8; t >= 0; --t)   // tap8 -> tap0 (matches prev rounds)
                        acc[o][p] = fmaf(px[t / 3][t % 3 + p], w[t], acc[o][p]);
                }
            }
        }
        __syncthreads();
    }

    const int oy = ty + row;
#pragma unroll
    for (int o = 0; o < 8; ++o) {
        const int oc = oc0 + og * 8 + o;
        const float bn_s = gamma[oc] / sqrtf(var[oc] + 1e-5f);
        const float bias = b1[oc], mu = mean[oc], bt = beta[oc];
        float* dst = y1 + ((size_t)(b * COUT1 + oc)) * HWSZ + oy * IMG + tx + cg * 8;
#pragma unroll
        for (int p = 0; p < 8; ++p) {
            float v = acc[o][p] + bias;
            v = (v - mu) * bn_s + bt;
            dst[p] = fmaxf(v, 0.0f);
        }
    }
}

// ---------------------------------------------------------------------------
// conv2: grouped 3x3, only the SEL channels; sigmoid where needed; -> d_out.
// ---------------------------------------------------------------------------
__global__ __launch_bounds__(256, 2) void conv2_kernel(
    const float* __restrict__ y1, const float* __restrict__ w2,
    const float* __restrict__ b2, float* __restrict__ out) {
    const int KH[6]   = {1, 1, 2, 1, 2, 4};
    const int REG[6]  = {OFF_LMAP, OFF_JMAP, OFF_JOFF, OFF_CMAP, OFF_COFF, OFF_LVEC};
    const int SIGF[6] = {1, 1, 0, 1, 0, 0};

    const int bz = blockIdx.z;
    const int b  = bz / 6;
    const int h  = bz % 6;
    const int k  = KH[h];
    const int tx = blockIdx.x * 16, ty = blockIdx.y * 16;
    const int lx = threadIdx.x, ly = threadIdx.y;
    const int tid = ly * 16 + lx;

    __shared__ float tin[4][18][33];
    float acc[4] = {0.0f, 0.0f, 0.0f, 0.0f};

    const float* yb = y1 + ((size_t)(b * COUT1 + h * 64)) * HWSZ;

    for (int ic0 = 0; ic0 < 64; ic0 += 4) {
        for (int i = tid; i < 1296; i += 256) {
            int c = i / 324, rem = i - c * 324;
            int r = rem / 18, col = rem - r * 18;
            int gy = ty - 1 + r, gx = tx - 1 + col;
            float v = 0.0f;
            if (gy >= 0 && gy < IMG && gx >= 0 && gx < IMG)
                v = yb[(size_t)(ic0 + c) * HWSZ + gy * IMG + gx];
            tin[c][r][col] = v;
        }
        __syncthreads();
#pragma unroll
        for (int c = 0; c < 4; ++c) {
            float n0 = tin[c][ly][lx],     n1 = tin[c][ly][lx + 1],     n2 = tin[c][ly][lx + 2];
            float n3 = tin[c][ly + 1][lx], n4 = tin[c][ly + 1][lx + 1], n5 = tin[c][ly + 1][lx + 2];
            float n6 = tin[c][ly + 2][lx], n7 = tin[c][ly + 2][lx + 1], n8 = tin[c][ly + 2][lx + 2];
#pragma unroll
            for (int o = 0; o < 4; ++o) {
                if (o < k) {
                    const float* wp = w2 + ((size_t)((h * 4 + o) * 64 + (ic0 + c))) * 9;
                    acc[o] = fmaf(n0, wp[0], fmaf(n1, wp[1], fmaf(n2, wp[2],
                             fmaf(n3, wp[3], fmaf(n4, wp[4], fmaf(n5, wp[5],
                             fmaf(n6, wp[6], fmaf(n7, wp[7], fmaf(n8, wp[8], acc[o])))))))));
                }
            }
        }
        __syncthreads();
    }

    const int p = (ty + ly) * IMG + tx + lx;
    for (int o = 0; o < k; ++o) {
        float v = acc[o] + b2[h * 4 + o];
        if (SIGF[h]) v = sigmoidf(v);
        out[REG[h] + ((size_t)(b * k + o)) * HWSZ + p] = v;
    }
}

// ---------------------------------------------------------------------------
// NMS on jmap + pack sort keys (value_bits<<32 | ~index  == lax.top_k order).
// ---------------------------------------------------------------------------
__global__ void nms_pack_kernel(const float* __restrict__ out,
                                u64* __restrict__ jsort,
                                u64* __restrict__ csort) {
    const int g = blockIdx.x;           // 0..399
    const int b = g / 100, q = g % 100;
    const int p = q * 256 + threadIdx.x;
    const float* jm = out + OFF_JMAP + (size_t)b * HWSZ;
    const float* cm = out + OFF_CMAP + (size_t)b * HWSZ;

    const int x = p % IMG, y = p / IMG;
    float v = jm[p];
    float mx = v;
#pragma unroll
    for (int dy = -1; dy <= 1; ++dy)
#pragma unroll
        for (int dx = -1; dx <= 1; ++dx) {
            int nx = x + dx, ny = y + dy;
            if (nx >= 0 && nx < IMG && ny >= 0 && ny < IMG)
                mx = fmaxf(mx, jm[ny * IMG + nx]);
        }
    float nmsv = (v == mx) ? v : 0.0f;

    u64 tagj = ((u64)__float_as_uint(nmsv) << 32)
             | (u64)(0xFFFFFFFFu - (unsigned)p);
    u64 tagc = ((u64)__float_as_uint(cm[p]) << 32)
             | (u64)(0xFFFFFFFFu - (unsigned)p);
    jsort[(size_t)b * 32768 + p] = tagj;
    csort[(size_t)b * 32768 + p] = tagc;
    if (q < 28) {                        // pad 25600..32767 with minimal keys
        int pp = 25600 + q * 256 + threadIdx.x;
        jsort[(size_t)b * 32768 + pp] = 0ull;
        csort[(size_t)b * 32768 + pp] = 0ull;
    }
}

// ---------------------------------------------------------------------------
// Hybrid bitonic sort, descending, 8 arrays x 32768 u64.
// ---------------------------------------------------------------------------
__global__ __launch_bounds__(1024) void sort64_ldsA(u64* __restrict__ buf) {
    __shared__ u64 s[8192];
    const size_t base = (size_t)blockIdx.x * 8192;   // 32 chunks (8 arrays x 4)
    const int cbase = (blockIdx.x & 3) * 8192;       // chunk offset within array
    for (int i = threadIdx.x; i < 8192; i += 1024) s[i] = buf[base + i];
    for (int k = 2; k <= 8192; k <<= 1)
        for (int j = k >> 1; j > 0; j >>= 1) {
            __syncthreads();
            for (int t = threadIdx.x; t < 4096; t += 1024) {
                int i = ((t & ~(j - 1)) << 1) | (t & (j - 1));
                int l = i | j;
                bool desc = (((i + cbase) & k) == 0);
                u64 x = s[i], y = s[l];
                if (desc ? (x < y) : (x > y)) { s[i] = y; s[l] = x; }
            }
        }
    __syncthreads();
    for (int i = threadIdx.x; i < 8192; i += 1024) buf[base + i] = s[i];
}

__global__ void sort64_gstep(u64* __restrict__ buf, int k, int j) {
    int t = blockIdx.x * 256 + threadIdx.x;          // 8 arrays * 16384 pairs
    int arr = t >> 14, p = t & 16383;
    int i = ((p & ~(j - 1)) << 1) | (p & (j - 1));
    int l = i | j;
    bool desc = ((i & k) == 0);
    u64* a = buf + (size_t)arr * 32768;
    u64 x = a[i], y = a[l];
    if (desc ? (x < y) : (x > y)) { a[i] = y; a[l] = x; }
}

__global__ __launch_bounds__(1024) void sort64_ldsB(u64* __restrict__ buf, int k) {
    __shared__ u64 s[8192];
    const size_t base = (size_t)blockIdx.x * 8192;
    const int cbase = (blockIdx.x & 3) * 8192;
    for (int i = threadIdx.x; i < 8192; i += 1024) s[i] = buf[base + i];
    for (int j = 4096; j > 0; j >>= 1) {
        __syncthreads();
        for (int t = threadIdx.x; t < 4096; t += 1024) {
            int i = ((t & ~(j - 1)) << 1) | (t & (j - 1));
            int l = i | j;
            bool desc = (((i + cbase) & k) == 0);
            u64 x = s[i], y = s[l];
            if (desc ? (x < y) : (x > y)) { s[i] = y; s[l] = x; }
        }
    }
    __syncthreads();
    for (int i = threadIdx.x; i < 8192; i += 1024) buf[base + i] = s[i];
}

// Full-LDS bitonic sort, ascending, 8192 int keys (one array per block).
__global__ __launch_bounds__(1024) void sort32_lds(int* __restrict__ buf) {
    __shared__ int s[8192];
    int* a = buf + (size_t)blockIdx.x * 8192;
    for (int i = threadIdx.x; i < 8192; i += 1024) s[i] = a[i];
    for (int k = 2; k <= 8192; k <<= 1)
        for (int j = k >> 1; j > 0; j >>= 1) {
            __syncthreads();
            for (int t = threadIdx.x; t < 4096; t += 1024) {
                int i = ((t & ~(j - 1)) << 1) | (t & (j - 1));
                int l = i | j;
                bool asc = ((i & k) == 0);
                int x = s[i], y = s[l];
                if (asc ? (x > y) : (x < y)) { s[i] = y; s[l] = x; }
            }
        }
    __syncthreads();
    for (int i = threadIdx.x; i < 8192; i += 1024) a[i] = s[i];
}

// Top-300 junctions: coordinates + validity.
__global__ void junction_kernel(const u64* __restrict__ jsort,
                                const float* __restrict__ out,
                                float* __restrict__ junc, int* __restrict__ jvalid) {
    const int b = blockIdx.x;
    const int t = threadIdx.x;
    if (t >= 300) return;
    u64 key = jsort[(size_t)b * 32768 + t];
    float score  = __uint_as_float((unsigned)(key >> 32));
    unsigned idx = 0xFFFFFFFFu - (unsigned)(key & 0xFFFFFFFFull);
    const float* j0 = out + OFF_JOFF + (size_t)(b * 2) * HWSZ;
    const float* j1 = j0 + HWSZ;
    float jx = (float)(idx % IMG) + j0[idx] + 0.5f;
    float jy = (float)(idx / IMG) + j1[idx] + 0.5f;
    junc[(size_t)(b * 300 + t) * 2]     = clip_coord(jx);
    junc[(size_t)(b * 300 + t) * 2 + 1] = clip_coord(jy);
    jvalid[b * 300 + t] = (score >= 0.008f) ? 1 : 0;
}

// Top-5000 centers -> line endpoints -> nearest-junction keys.
__global__ void lines_kernel(const u64* __restrict__ csort,
                             const float* __restrict__ junc,
                             const int* __restrict__ jvalid,
                             const float* __restrict__ out,
                             int* __restrict__ lkeys) {
    const int b = blockIdx.y;
    const int t = blockIdx.x * 256 + threadIdx.x;

    __shared__ float jx[300], jy[300];
    __shared__ int jv[300];
    for (int i = threadIdx.x; i < 300; i += 256) {
        jx[i] = junc[(size_t)(b * 300 + i) * 2];
        jy[i] = junc[(size_t)(b * 300 + i) * 2 + 1];
        jv[i] = jvalid[b * 300 + i];
    }
    __syncthreads();

    if (t >= 8192) return;
    if (t >= 5000) { lkeys[b * 8192 + t] = 0x7FFFFFFF; return; }

    u64 key = csort[(size_t)b * 32768 + t];
    unsigned idx = 0xFFFFFFFFu - (unsigned)(key & 0xFFFFFFFFull);
    const float* c0 = out + OFF_COFF + (size_t)(b * 2) * HWSZ;
    const float* c1 = c0 + HWSZ;
    const float* lv = out + OFF_LVEC + (size_t)(b * 4) * HWSZ;

    float cx = (float)(idx % IMG) + c0[idx] + 0.5f;
    float cy = (float)(idx / IMG) + c1[idx] + 0.5f;
    float e0x = clip_coord(cx + lv[idx]);
    float e0y = clip_coord(cy + lv[HWSZ + idx]);
    float e1x = clip_coord(cx + lv[2 * HWSZ + idx]);
    float e1y = clip_coord(cy + lv[3 * HWSZ + idx]);

    float m1 = 1e18f, m2 = 1e18f;
    int i1 = 0, i2 = 0;
    for (int j = 0; j < 300; ++j) {
        if (jv[j]) {
            float dx = e0x - jx[j], dy = e0y - jy[j];
            float d = dx * dx + dy * dy;
            if (d < m1) { m1 = d; i1 = j; }
            dx = e1x - jx[j]; dy = e1y - jy[j];
            d = dx * dx + dy * dy;
            if (d < m2) { m2 = d; i2 = j; }
        }
    }
    int imin = min(i1, i2), imax = max(i1, i2);
    lkeys[b * 8192 + t] = (i1 != i2) ? (imin * 300 + imax) : BIGK;
}

// Dedup sorted keys -> line segments + mask.
__global__ void finalize_kernel(const int* __restrict__ lkeys,
                                const float* __restrict__ junc,
                                float* __restrict__ out) {
    const int b = blockIdx.y;
    const int t = blockIdx.x * 256 + threadIdx.x;
    if (t >= 5000) return;
    const int* lk = lkeys + b * 8192;
    int sk = lk[t];
    bool first = ((t == 0) || (sk != lk[t - 1])) && (sk < BIGK);
    int a  = first ? sk / 300 : 0;
    int bb = first ? sk % 300 : 0;
    float p0x = junc[(size_t)(b * 300 + a) * 2];
    float p0y = junc[(size_t)(b * 300 + a) * 2 + 1];
    float p1x = junc[(size_t)(b * 300 + bb) * 2];
    float p1y = junc[(size_t)(b * 300 + bb) * 2 + 1];
    if (p0y > p1y) {
        float tx = p0x; p0x = p1x; p1x = tx;
        float ty = p0y; p0y = p1y; p1y = ty;
    }
    size_t base = OFF_LOI + (size_t)(b * 5000 + t) * 4;
    out[base]     = p0x;
    out[base + 1] = p0y;
    out[base + 2] = p1x;
    out[base + 3] = p1y;
    out[OFF_MASK + b * 5000 + t] = first ? 1.0f : 0.0f;
}

extern "C" void kernel_launch(void* const* d_in, const int* in_sizes, int n_in,
                              void* d_out, int out_size, void* d_ws, size_t ws_size,
                              hipStream_t stream) {
    const float* feat  = (const float*)d_in[0];
    const float* w1    = (const float*)d_in[1];
    const float* b1    = (const float*)d_in[2];
    const float* gamma = (const float*)d_in[3];
    const float* beta  = (const float*)d_in[4];
    const float* mean  = (const float*)d_in[5];
    const float* var   = (const float*)d_in[6];
    const float* w2    = (const float*)d_in[7];
    const float* b2    = (const float*)d_in[8];
    float* out = (float*)d_out;
    char*  ws  = (char*)d_ws;

    if (ws_size < WS_NEED) return;   // ~159.6 MB needed

    float* y1 = (float*)(ws + WS_Y1);
    u64* jsort = (u64*)(ws + WS_JSORT);
    float* junc = (float*)(ws + WS_JUNC);
    int* jvalid = (int*)(ws + WS_JVAL);
    int* lkeys  = (int*)(ws + WS_LKEY);
    u64* csort = (u64*)(ws + WS_CSORT);

    // 1. conv1 + BN + ReLU -> y1   (tile 16x32, 32 oc; grid 5x10x48)
    conv1_kernel<<<dim3(5, 10, NB * 12), dim3(256), 0, stream>>>(
        feat, w1, b1, gamma, beta, mean, var, y1);

    // 2. conv2 (grouped, SEL channels only) -> maps in d_out
    conv2_kernel<<<dim3(10, 10, NB * 6), dim3(16, 16), 0, stream>>>(y1, w2, b2, out);

    // 3. NMS + pack sort keys
    nms_pack_kernel<<<dim3(NB * 100), dim3(256), 0, stream>>>(out, jsort, csort);

    // 4. hybrid bitonic sort of 8 u64 arrays (4 jmap + 4 cmap, contiguous)
    sort64_ldsA<<<dim3(32), dim3(1024), 0, stream>>>(jsort);
    sort64_gstep<<<dim3(512), dim3(256), 0, stream>>>(jsort, 16384, 8192);
    sort64_ldsB<<<dim3(32), dim3(1024), 0, stream>>>(jsort, 16384);
    sort64_gstep<<<dim3(512), dim3(256), 0, stream>>>(jsort, 32768, 16384);
    sort64_gstep<<<dim3(512), dim3(256), 0, stream>>>(jsort, 32768, 8192);
    sort64_ldsB<<<dim3(32), dim3(1024), 0, stream>>>(jsort, 32768);

    // 5. junctions
    junction_kernel<<<dim3(NB), dim3(320), 0, stream>>>(jsort, out, junc, jvalid);

    // 6. line keys
    lines_kernel<<<dim3(32, NB), dim3(256), 0, stream>>>(csort, junc, jvalid, out, lkeys);

    // 7. sort line keys ascending (full LDS)
    sort32_lds<<<dim3(NB), dim3(1024), 0, stream>>>(lkeys);

    // 8. dedup + emit loi/mask
    finalize_kernel<<<dim3(20, NB), dim3(256), 0, stream>>>(lkeys, junc, out);
}

// Round 5
// 2339.678 us; speedup vs baseline: 2.3815x; 1.3519x over previous
//
#include <hip/hip_runtime.h>
#include <math.h>

#define IMG   160
#define HWSZ  25600
#define NB    4
#define CIN   256
#define COUT1 384
#define BIGK  90000

// output offsets (in floats)
#define OFF_LMAP 0
#define OFF_JMAP 102400
#define OFF_JOFF 204800
#define OFF_CMAP 409600
#define OFF_COFF 512000
#define OFF_LVEC 716800
#define OFF_LOI  1126400
#define OFF_MASK 1206400

// workspace offsets (bytes)
static const size_t WS_Y1    = 0;
static const size_t WS_JSORT = (size_t)NB * COUT1 * HWSZ * 4;            // 157286400
static const size_t WS_CSORT = WS_JSORT + (size_t)NB * 32768 * 8;
static const size_t WS_JUNC  = WS_CSORT + (size_t)NB * 32768 * 8;
static const size_t WS_JVAL  = WS_JUNC + (size_t)NB * 300 * 2 * 4;
static const size_t WS_LKEY  = WS_JVAL + (size_t)NB * 300 * 4;
static const size_t WS_WPK   = WS_LKEY + (size_t)NB * 8192 * 4;
// Wpack: 3 octiles * 72 chunks * (128 rows * 68 shorts) * 2 B = 3,760,128
static const size_t WS_NEED  = WS_WPK + (size_t)3 * 72 * 128 * 68 * 2;

typedef unsigned long long u64;
typedef __attribute__((ext_vector_type(8))) short short8;
typedef __attribute__((ext_vector_type(4))) float f32x4;
typedef __attribute__((ext_vector_type(4))) int int4v;

union frag_u { short8 s8; u64 u[2]; };

__device__ __forceinline__ float clip_coord(float v) {
    return fminf(fmaxf(v, 0.0f), 159.9999f);
}
__device__ __forceinline__ float sigmoidf(float v) {
    return 1.0f / (1.0f + expf(-v));
}
__device__ __forceinline__ unsigned short f2bf(float f) {   // RNE
    unsigned u = __float_as_uint(f);
    return (unsigned short)((u + 0x7FFFu + ((u >> 16) & 1u)) >> 16);
}
__device__ __forceinline__ float bf2f(unsigned short h) {
    return __uint_as_float((unsigned)h << 16);
}

// ---------------------------------------------------------------------------
// Pre-pack w1 into the exact LDS image consumed by conv1_mfma:
//   Wpack[octile 3][chunk 72][ocl 128][68 shorts: t0 icl0..31 | t1 icl0..31 | pad4]
// term0 = bf16_rne(w), term1 = bf16_rne(w - term0).   chunk = tap*8 + ic/32.
// ---------------------------------------------------------------------------
__global__ void wpack_kernel(const float* __restrict__ w1, short* __restrict__ wpk) {
    int e = blockIdx.x * 256 + threadIdx.x;          // 3*72*8704 = 1,880,064
    int page = e / 8704, pos = e - page * 8704;      // page = octile*72 + chunk
    int ocl = pos / 68, q = pos - ocl * 68;
    short outv = 0;
    if (q < 64) {
        int term = q >> 5, icl = q & 31;
        int octile = page / 72, chunk = page - octile * 72;
        int tap = chunk >> 3, icc = chunk & 7;
        int oc = octile * 128 + ocl, ic = icc * 32 + icl;
        float a = w1[((size_t)oc * CIN + ic) * 9 + tap];
        unsigned short hi = f2bf(a);
        outv = (term == 0) ? (short)hi : (short)f2bf(a - bf2f(hi));
    }
    wpk[e] = outv;
}

// ---------------------------------------------------------------------------
// conv1 via MFMA implicit GEMM, 2-term bf16 split (4 products -> ~fp32 accuracy).
// Block: 128 oc x 128 px; 4 waves of 64x64 (4x4 frags of 16x16x32).
// K = (tap, ic), 72 chunks of 32.  A (weights) staged from Wpack by flat copy;
// B (pixels) im2col'd + split on the fly.  LDS rows padded to 68 shorts.
// ---------------------------------------------------------------------------
__global__ __launch_bounds__(256, 2) void conv1_mfma(
    const float* __restrict__ feat, const short* __restrict__ wpk,
    const float* __restrict__ b1, const float* __restrict__ gamma,
    const float* __restrict__ beta, const float* __restrict__ mean,
    const float* __restrict__ var, float* __restrict__ y1) {
    const int pxtile = blockIdx.x;      // 0..799
    const int octile = blockIdx.y;      // 0..2
    const int tid  = threadIdx.x;
    const int lane = tid & 63;
    const int w    = tid >> 6;          // wave 0..3
    const int wm   = w & 1;             // oc-half
    const int wn   = w >> 1;            // px-half
    const int quad = lane >> 4;
    const int l15  = lane & 15;

    __shared__ short Alds[128 * 68];    // [ocl][t0 icl32 | t1 icl32 | pad]
    __shared__ short Blds[128 * 68];    // [pxl][t0 icl32 | t1 icl32 | pad]

    // B-staging invariants: thread -> (pxl, icl half)
    const int pxl_s = tid & 127;
    const int ich16 = tid >> 7;                     // 0/1 -> icl base 0/16
    const int p     = pxtile * 128 + pxl_s;
    const int bb    = p / HWSZ, hw = p - bb * HWSZ;
    const int yy0   = hw / IMG, xx0 = hw - yy0 * IMG;

    f32x4 acc[4][4];
#pragma unroll
    for (int mi = 0; mi < 4; ++mi)
#pragma unroll
        for (int ni = 0; ni < 4; ++ni) acc[mi][ni] = (f32x4){0.f, 0.f, 0.f, 0.f};

    const int4v* asrc_base = (const int4v*)(wpk + (size_t)octile * 72 * 8704);
    unsigned* Bd = (unsigned*)Blds;

    for (int chunk = 0; chunk < 72; ++chunk) {
        const int tap = chunk >> 3, icc = chunk & 7;
        const int dy = tap / 3 - 1, dx = tap % 3 - 1;
        __syncthreads();
        // ---- stage A: flat copy of 17408 B (1088 int4)
        {
            const int4v* asrc = asrc_base + (size_t)chunk * 1088;
            int4v* adst = (int4v*)Alds;
#pragma unroll
            for (int i = 0; i < 5; ++i) {
                int idx = tid + i * 256;
                if (idx < 1088) adst[idx] = asrc[idx];
            }
        }
        // ---- stage B: im2col + split, 16 icl per thread
        {
            const int yy = yy0 + dy, xx = xx0 + dx;
            const bool valid = ((unsigned)yy < IMG) && ((unsigned)xx < IMG);
            const float* fsrc = feat + ((size_t)bb * CIN + icc * 32 + ich16 * 16) * HWSZ
                                     + (valid ? (yy * IMG + xx) : 0);
#pragma unroll
            for (int e2 = 0; e2 < 8; ++e2) {
                float v0 = valid ? fsrc[(size_t)(2 * e2) * HWSZ]     : 0.0f;
                float v1 = valid ? fsrc[(size_t)(2 * e2 + 1) * HWSZ] : 0.0f;
                unsigned short h0 = f2bf(v0), h1 = f2bf(v1);
                unsigned short m0 = f2bf(v0 - bf2f(h0)), m1 = f2bf(v1 - bf2f(h1));
                int icl2 = ich16 * 8 + e2;
                Bd[pxl_s * 34 + icl2]      = (unsigned)h0 | ((unsigned)h1 << 16);
                Bd[pxl_s * 34 + 16 + icl2] = (unsigned)m0 | ((unsigned)m1 << 16);
            }
        }
        __syncthreads();
        // ---- fragment loads (2 terms x 4 tiles each side), 2 x b64 per frag
        frag_u Af[2][4], Bf[2][4];
#pragma unroll
        for (int t = 0; t < 2; ++t) {
#pragma unroll
            for (int mi = 0; mi < 4; ++mi) {
                int off = (wm * 64 + mi * 16 + l15) * 68 + t * 32 + quad * 8;
                Af[t][mi].u[0] = *(const u64*)&Alds[off];
                Af[t][mi].u[1] = *(const u64*)&Alds[off + 4];
            }
#pragma unroll
            for (int ni = 0; ni < 4; ++ni) {
                int off = (wn * 64 + ni * 16 + l15) * 68 + t * 32 + quad * 8;
                Bf[t][ni].u[0] = *(const u64*)&Blds[off];
                Bf[t][ni].u[1] = *(const u64*)&Blds[off + 4];
            }
        }
        // ---- 4 products per (mi,ni): hihi, himid, midhi, midmid
#pragma unroll
        for (int mi = 0; mi < 4; ++mi)
#pragma unroll
            for (int ni = 0; ni < 4; ++ni) {
                acc[mi][ni] = __builtin_amdgcn_mfma_f32_16x16x32_bf16(
                    Af[0][mi].s8, Bf[0][ni].s8, acc[mi][ni], 0, 0, 0);
                acc[mi][ni] = __builtin_amdgcn_mfma_f32_16x16x32_bf16(
                    Af[0][mi].s8, Bf[1][ni].s8, acc[mi][ni], 0, 0, 0);
                acc[mi][ni] = __builtin_amdgcn_mfma_f32_16x16x32_bf16(
                    Af[1][mi].s8, Bf[0][ni].s8, acc[mi][ni], 0, 0, 0);
                acc[mi][ni] = __builtin_amdgcn_mfma_f32_16x16x32_bf16(
                    Af[1][mi].s8, Bf[1][ni].s8, acc[mi][ni], 0, 0, 0);
            }
    }

    // ---- epilogue: BN + ReLU, C/D layout col=lane&15 (px), row=quad*4+reg (oc)
#pragma unroll
    for (int ni = 0; ni < 4; ++ni) {
        const int px = pxtile * 128 + wn * 64 + ni * 16 + l15;
        const int b2 = px / HWSZ, hw2 = px - b2 * HWSZ;
        float* ybase = y1 + (size_t)b2 * COUT1 * HWSZ + hw2;
#pragma unroll
        for (int mi = 0; mi < 4; ++mi)
#pragma unroll
            for (int r = 0; r < 4; ++r) {
                const int oc = octile * 128 + wm * 64 + mi * 16 + quad * 4 + r;
                float v = acc[mi][ni][r] + b1[oc];
                v = (v - mean[oc]) * (gamma[oc] / sqrtf(var[oc] + 1e-5f)) + beta[oc];
                ybase[(size_t)oc * HWSZ] = fmaxf(v, 0.0f);
            }
    }
}

// ---------------------------------------------------------------------------
// conv2: grouped 3x3, only the SEL channels; sigmoid where needed; -> d_out.
// ---------------------------------------------------------------------------
__global__ __launch_bounds__(256, 2) void conv2_kernel(
    const float* __restrict__ y1, const float* __restrict__ w2,
    const float* __restrict__ b2, float* __restrict__ out) {
    const int KH[6]   = {1, 1, 2, 1, 2, 4};
    const int REG[6]  = {OFF_LMAP, OFF_JMAP, OFF_JOFF, OFF_CMAP, OFF_COFF, OFF_LVEC};
    const int SIGF[6] = {1, 1, 0, 1, 0, 0};

    const int bz = blockIdx.z;
    const int b  = bz / 6;
    const int h  = bz % 6;
    const int k  = KH[h];
    const int tx = blockIdx.x * 16, ty = blockIdx.y * 16;
    const int lx = threadIdx.x, ly = threadIdx.y;
    const int tid = ly * 16 + lx;

    __shared__ float tin[4][18][33];
    float acc[4] = {0.0f, 0.0f, 0.0f, 0.0f};

    const float* yb = y1 + ((size_t)(b * COUT1 + h * 64)) * HWSZ;

    for (int ic0 = 0; ic0 < 64; ic0 += 4) {
        for (int i = tid; i < 1296; i += 256) {
            int c = i / 324, rem = i - c * 324;
            int r = rem / 18, col = rem - r * 18;
            int gy = ty - 1 + r, gx = tx - 1 + col;
            float v = 0.0f;
            if (gy >= 0 && gy < IMG && gx >= 0 && gx < IMG)
                v = yb[(size_t)(ic0 + c) * HWSZ + gy * IMG + gx];
            tin[c][r][col] = v;
        }
        __syncthreads();
#pragma unroll
        for (int c = 0; c < 4; ++c) {
            float n0 = tin[c][ly][lx],     n1 = tin[c][ly][lx + 1],     n2 = tin[c][ly][lx + 2];
            float n3 = tin[c][ly + 1][lx], n4 = tin[c][ly + 1][lx + 1], n5 = tin[c][ly + 1][lx + 2];
            float n6 = tin[c][ly + 2][lx], n7 = tin[c][ly + 2][lx + 1], n8 = tin[c][ly + 2][lx + 2];
#pragma unroll
            for (int o = 0; o < 4; ++o) {
                if (o < k) {
                    const float* wp = w2 + ((size_t)((h * 4 + o) * 64 + (ic0 + c))) * 9;
                    acc[o] = fmaf(n0, wp[0], fmaf(n1, wp[1], fmaf(n2, wp[2],
                             fmaf(n3, wp[3], fmaf(n4, wp[4], fmaf(n5, wp[5],
                             fmaf(n6, wp[6], fmaf(n7, wp[7], fmaf(n8, wp[8], acc[o])))))))));
                }
            }
        }
        __syncthreads();
    }

    const int p = (ty + ly) * IMG + tx + lx;
    for (int o = 0; o < k; ++o) {
        float v = acc[o] + b2[h * 4 + o];
        if (SIGF[h]) v = sigmoidf(v);
        out[REG[h] + ((size_t)(b * k + o)) * HWSZ + p] = v;
    }
}

// ---------------------------------------------------------------------------
// NMS on jmap + pack sort keys (value_bits<<32 | ~index  == lax.top_k order).
// ---------------------------------------------------------------------------
__global__ void nms_pack_kernel(const float* __restrict__ out,
                                u64* __restrict__ jsort,
                                u64* __restrict__ csort) {
    const int g = blockIdx.x;           // 0..399
    const int b = g / 100, q = g % 100;
    const int p = q * 256 + threadIdx.x;
    const float* jm = out + OFF_JMAP + (size_t)b * HWSZ;
    const float* cm = out + OFF_CMAP + (size_t)b * HWSZ;

    const int x = p % IMG, y = p / IMG;
    float v = jm[p];
    float mx = v;
#pragma unroll
    for (int dy = -1; dy <= 1; ++dy)
#pragma unroll
        for (int dx = -1; dx <= 1; ++dx) {
            int nx = x + dx, ny = y + dy;
            if (nx >= 0 && nx < IMG && ny >= 0 && ny < IMG)
                mx = fmaxf(mx, jm[ny * IMG + nx]);
        }
    float nmsv = (v == mx) ? v : 0.0f;

    u64 tagj = ((u64)__float_as_uint(nmsv) << 32)
             | (u64)(0xFFFFFFFFu - (unsigned)p);
    u64 tagc = ((u64)__float_as_uint(cm[p]) << 32)
             | (u64)(0xFFFFFFFFu - (unsigned)p);
    jsort[(size_t)b * 32768 + p] = tagj;
    csort[(size_t)b * 32768 + p] = tagc;
    if (q < 28) {                        // pad 25600..32767 with minimal keys
        int pp = 25600 + q * 256 + threadIdx.x;
        jsort[(size_t)b * 32768 + pp] = 0ull;
        csort[(size_t)b * 32768 + pp] = 0ull;
    }
}

// ---------------------------------------------------------------------------
// Hybrid bitonic sort, descending, 8 arrays x 32768 u64.
// ---------------------------------------------------------------------------
__global__ __launch_bounds__(1024) void sort64_ldsA(u64* __restrict__ buf) {
    __shared__ u64 s[8192];
    const size_t base = (size_t)blockIdx.x * 8192;   // 32 chunks (8 arrays x 4)
    const int cbase = (blockIdx.x & 3) * 8192;       // chunk offset within array
    for (int i = threadIdx.x; i < 8192; i += 1024) s[i] = buf[base + i];
    for (int k = 2; k <= 8192; k <<= 1)
        for (int j = k >> 1; j > 0; j >>= 1) {
            __syncthreads();
            for (int t = threadIdx.x; t < 4096; t += 1024) {
                int i = ((t & ~(j - 1)) << 1) | (t & (j - 1));
                int l = i | j;
                bool desc = (((i + cbase) & k) == 0);
                u64 x = s[i], y = s[l];
                if (desc ? (x < y) : (x > y)) { s[i] = y; s[l] = x; }
            }
        }
    __syncthreads();
    for (int i = threadIdx.x; i < 8192; i += 1024) buf[base + i] = s[i];
}

__global__ void sort64_gstep(u64* __restrict__ buf, int k, int j) {
    int t = blockIdx.x * 256 + threadIdx.x;          // 8 arrays * 16384 pairs
    int arr = t >> 14, p = t & 16383;
    int i = ((p & ~(j - 1)) << 1) | (p & (j - 1));
    int l = i | j;
    bool desc = ((i & k) == 0);
    u64* a = buf + (size_t)arr * 32768;
    u64 x = a[i], y = a[l];
    if (desc ? (x < y) : (x > y)) { a[i] = y; a[l] = x; }
}

__global__ __launch_bounds__(1024) void sort64_ldsB(u64* __restrict__ buf, int k) {
    __shared__ u64 s[8192];
    const size_t base = (size_t)blockIdx.x * 8192;
    const int cbase = (blockIdx.x & 3) * 8192;
    for (int i = threadIdx.x; i < 8192; i += 1024) s[i] = buf[base + i];
    for (int j = 4096; j > 0; j >>= 1) {
        __syncthreads();
        for (int t = threadIdx.x; t < 4096; t += 1024) {
            int i = ((t & ~(j - 1)) << 1) | (t & (j - 1));
            int l = i | j;
            bool desc = (((i + cbase) & k) == 0);
            u64 x = s[i], y = s[l];
            if (desc ? (x < y) : (x > y)) { s[i] = y; s[l] = x; }
        }
    }
    __syncthreads();
    for (int i = threadIdx.x; i < 8192; i += 1024) buf[base + i] = s[i];
}

// Full-LDS bitonic sort, ascending, 8192 int keys (one array per block).
__global__ __launch_bounds__(1024) void sort32_lds(int* __restrict__ buf) {
    __shared__ int s[8192];
    int* a = buf + (size_t)blockIdx.x * 8192;
    for (int i = threadIdx.x; i < 8192; i += 1024) s[i] = a[i];
    for (int k = 2; k <= 8192; k <<= 1)
        for (int j = k >> 1; j > 0; j >>= 1) {
            __syncthreads();
            for (int t = threadIdx.x; t < 4096; t += 1024) {
                int i = ((t & ~(j - 1)) << 1) | (t & (j - 1));
                int l = i | j;
                bool asc = ((i & k) == 0);
                int x = s[i], y = s[l];
                if (asc ? (x > y) : (x < y)) { s[i] = y; s[l] = x; }
            }
        }
    __syncthreads();
    for (int i = threadIdx.x; i < 8192; i += 1024) a[i] = s[i];
}

// Top-300 junctions: coordinates + validity.
__global__ void junction_kernel(const u64* __restrict__ jsort,
                                const float* __restrict__ out,
                                float* __restrict__ junc, int* __restrict__ jvalid) {
    const int b = blockIdx.x;
    const int t = threadIdx.x;
    if (t >= 300) return;
    u64 key = jsort[(size_t)b * 32768 + t];
    float score  = __uint_as_float((unsigned)(key >> 32));
    unsigned idx = 0xFFFFFFFFu - (unsigned)(key & 0xFFFFFFFFull);
    const float* j0 = out + OFF_JOFF + (size_t)(b * 2) * HWSZ;
    const float* j1 = j0 + HWSZ;
    float jx = (float)(idx % IMG) + j0[idx] + 0.5f;
    float jy = (float)(idx / IMG) + j1[idx] + 0.5f;
    junc[(size_t)(b * 300 + t) * 2]     = clip_coord(jx);
    junc[(size_t)(b * 300 + t) * 2 + 1] = clip_coord(jy);
    jvalid[b * 300 + t] = (score >= 0.008f) ? 1 : 0;
}

// Top-5000 centers -> line endpoints -> nearest-junction keys.
__global__ void lines_kernel(const u64* __restrict__ csort,
                             const float* __restrict__ junc,
                             const int* __restrict__ jvalid,
                             const float* __restrict__ out,
                             int* __restrict__ lkeys) {
    const int b = blockIdx.y;
    const int t = blockIdx.x * 256 + threadIdx.x;

    __shared__ float jx[300], jy[300];
    __shared__ int jv[300];
    for (int i = threadIdx.x; i < 300; i += 256) {
        jx[i] = junc[(size_t)(b * 300 + i) * 2];
        jy[i] = junc[(size_t)(b * 300 + i) * 2 + 1];
        jv[i] = jvalid[b * 300 + i];
    }
    __syncthreads();

    if (t >= 8192) return;
    if (t >= 5000) { lkeys[b * 8192 + t] = 0x7FFFFFFF; return; }

    u64 key = csort[(size_t)b * 32768 + t];
    unsigned idx = 0xFFFFFFFFu - (unsigned)(key & 0xFFFFFFFFull);
    const float* c0 = out + OFF_COFF + (size_t)(b * 2) * HWSZ;
    const float* c1 = c0 + HWSZ;
    const float* lv = out + OFF_LVEC + (size_t)(b * 4) * HWSZ;

    float cx = (float)(idx % IMG) + c0[idx] + 0.5f;
    float cy = (float)(idx / IMG) + c1[idx] + 0.5f;
    float e0x = clip_coord(cx + lv[idx]);
    float e0y = clip_coord(cy + lv[HWSZ + idx]);
    float e1x = clip_coord(cx + lv[2 * HWSZ + idx]);
    float e1y = clip_coord(cy + lv[3 * HWSZ + idx]);

    float m1 = 1e18f, m2 = 1e18f;
    int i1 = 0, i2 = 0;
    for (int j = 0; j < 300; ++j) {
        if (jv[j]) {
            float dx = e0x - jx[j], dy = e0y - jy[j];
            float d = dx * dx + dy * dy;
            if (d < m1) { m1 = d; i1 = j; }
            dx = e1x - jx[j]; dy = e1y - jy[j];
            d = dx * dx + dy * dy;
            if (d < m2) { m2 = d; i2 = j; }
        }
    }
    int imin = min(i1, i2), imax = max(i1, i2);
    lkeys[b * 8192 + t] = (i1 != i2) ? (imin * 300 + imax) : BIGK;
}

// Dedup sorted keys -> line segments + mask.
__global__ void finalize_kernel(const int* __restrict__ lkeys,
                                const float* __restrict__ junc,
                                float* __restrict__ out) {
    const int b = blockIdx.y;
    const int t = blockIdx.x * 256 + threadIdx.x;
    if (t >= 5000) return;
    const int* lk = lkeys + b * 8192;
    int sk = lk[t];
    bool first = ((t == 0) || (sk != lk[t - 1])) && (sk < BIGK);
    int a  = first ? sk / 300 : 0;
    int bb = first ? sk % 300 : 0;
    float p0x = junc[(size_t)(b * 300 + a) * 2];
    float p0y = junc[(size_t)(b * 300 + a) * 2 + 1];
    float p1x = junc[(size_t)(b * 300 + bb) * 2];
    float p1y = junc[(size_t)(b * 300 + bb) * 2 + 1];
    if (p0y > p1y) {
        float tx = p0x; p0x = p1x; p1x = tx;
        float ty = p0y; p0y = p1y; p1y = ty;
    }
    size_t base = OFF_LOI + (size_t)(b * 5000 + t) * 4;
    out[base]     = p0x;
    out[base + 1] = p0y;
    out[base + 2] = p1x;
    out[base + 3] = p1y;
    out[OFF_MASK + b * 5000 + t] = first ? 1.0f : 0.0f;
}

extern "C" void kernel_launch(void* const* d_in, const int* in_sizes, int n_in,
                              void* d_out, int out_size, void* d_ws, size_t ws_size,
                              hipStream_t stream) {
    const float* feat  = (const float*)d_in[0];
    const float* w1    = (const float*)d_in[1];
    const float* b1    = (const float*)d_in[2];
    const float* gamma = (const float*)d_in[3];
    const float* beta  = (const float*)d_in[4];
    const float* mean  = (const float*)d_in[5];
    const float* var   = (const float*)d_in[6];
    const float* w2    = (const float*)d_in[7];
    const float* b2    = (const float*)d_in[8];
    float* out = (float*)d_out;
    char*  ws  = (char*)d_ws;

    if (ws_size < WS_NEED) return;   // ~163 MB needed

    float* y1 = (float*)(ws + WS_Y1);
    u64* jsort = (u64*)(ws + WS_JSORT);
    float* junc = (float*)(ws + WS_JUNC);
    int* jvalid = (int*)(ws + WS_JVAL);
    int* lkeys  = (int*)(ws + WS_LKEY);
    u64* csort = (u64*)(ws + WS_CSORT);
    short* wpk = (short*)(ws + WS_WPK);

    // 0. pre-split/pack conv1 weights into MFMA staging layout
    wpack_kernel<<<dim3(7344), dim3(256), 0, stream>>>(w1, wpk);

    // 1. conv1 + BN + ReLU -> y1  (MFMA implicit GEMM, 128oc x 128px blocks)
    conv1_mfma<<<dim3(800, 3), dim3(256), 0, stream>>>(
        feat, wpk, b1, gamma, beta, mean, var, y1);

    // 2. conv2 (grouped, SEL channels only) -> maps in d_out
    conv2_kernel<<<dim3(10, 10, NB * 6), dim3(16, 16), 0, stream>>>(y1, w2, b2, out);

    // 3. NMS + pack sort keys
    nms_pack_kernel<<<dim3(NB * 100), dim3(256), 0, stream>>>(out, jsort, csort);

    // 4. hybrid bitonic sort of 8 u64 arrays (4 jmap + 4 cmap, contiguous)
    sort64_ldsA<<<dim3(32), dim3(1024), 0, stream>>>(jsort);
    sort64_gstep<<<dim3(512), dim3(256), 0, stream>>>(jsort, 16384, 8192);
    sort64_ldsB<<<dim3(32), dim3(1024), 0, stream>>>(jsort, 16384);
    sort64_gstep<<<dim3(512), dim3(256), 0, stream>>>(jsort, 32768, 16384);
    sort64_gstep<<<dim3(512), dim3(256), 0, stream>>>(jsort, 32768, 8192);
    sort64_ldsB<<<dim3(32), dim3(1024), 0, stream>>>(jsort, 32768);

    // 5. junctions
    junction_kernel<<<dim3(NB), dim3(320), 0, stream>>>(jsort, out, junc, jvalid);

    // 6. line keys
    lines_kernel<<<dim3(32, NB), dim3(256), 0, stream>>>(csort, junc, jvalid, out, lkeys);

    // 7. sort line keys ascending (full LDS)
    sort32_lds<<<dim3(NB), dim3(1024), 0, stream>>>(lkeys);

    // 8. dedup + emit loi/mask
    finalize_kernel<<<dim3(20, NB), dim3(256), 0, stream>>>(lkeys, junc, out);
}

// Round 6
// 1870.052 us; speedup vs baseline: 2.9795x; 1.2511x over previous
//
#include <hip/hip_runtime.h>
#include <math.h>

#define IMG   160
#define HWSZ  25600
#define NB    4
#define CIN   256
#define COUT1 384
#define BIGK  90000

// output offsets (in floats)
#define OFF_LMAP 0
#define OFF_JMAP 102400
#define OFF_JOFF 204800
#define OFF_CMAP 409600
#define OFF_COFF 512000
#define OFF_LVEC 716800
#define OFF_LOI  1126400
#define OFF_MASK 1206400

// workspace offsets (bytes)
static const size_t WS_Y1    = 0;
static const size_t WS_JSORT = (size_t)NB * COUT1 * HWSZ * 4;            // 157286400
static const size_t WS_CSORT = WS_JSORT + (size_t)NB * 32768 * 8;
static const size_t WS_JUNC  = WS_CSORT + (size_t)NB * 32768 * 8;
static const size_t WS_JVAL  = WS_JUNC + (size_t)NB * 300 * 2 * 4;
static const size_t WS_LKEY  = WS_JVAL + (size_t)NB * 300 * 4;
static const size_t WS_WPK   = WS_LKEY + (size_t)NB * 8192 * 4;
// Wpack: 12 octiles * 8 icc * 9 taps * 32 ocl * 68 shorts * 2 B = 3,760,128
static const size_t WS_NEED  = WS_WPK + (size_t)12 * 8 * 9 * 32 * 68 * 2;

typedef unsigned long long u64;
typedef __attribute__((ext_vector_type(8))) short short8;
typedef __attribute__((ext_vector_type(4))) float f32x4;
typedef __attribute__((ext_vector_type(4))) int int4v;

union frag_u { short8 s8; u64 u[2]; };

__device__ __forceinline__ float clip_coord(float v) {
    return fminf(fmaxf(v, 0.0f), 159.9999f);
}
__device__ __forceinline__ float sigmoidf(float v) {
    return 1.0f / (1.0f + expf(-v));
}
__device__ __forceinline__ unsigned short f2bf(float f) {   // RNE
    unsigned u = __float_as_uint(f);
    return (unsigned short)((u + 0x7FFFu + ((u >> 16) & 1u)) >> 16);
}
__device__ __forceinline__ float bf2f(unsigned short h) {
    return __uint_as_float((unsigned)h << 16);
}

// ---------------------------------------------------------------------------
// Pre-pack w1 into the LDS image consumed by conv1_mfma:
//   Wpack[octile 12][icc 8][tap 9][ocl 32][68 shorts: t0 icl0..31|t1 icl0..31|pad]
// term0 = bf16_rne(w), term1 = bf16_rne(w - term0).
// ---------------------------------------------------------------------------
__global__ void wpack_kernel(const float* __restrict__ w1, short* __restrict__ wpk) {
    int e = blockIdx.x * 256 + threadIdx.x;      // 12*8*19584 = 1,880,064
    int page = e / 19584, pos = e - page * 19584;    // page = octile*8 + icc
    int tap = pos / 2176, rem = pos - tap * 2176;
    int ocl = rem / 68, q = rem - ocl * 68;
    short outv = 0;
    if (q < 64) {
        int term = q >> 5, icl = q & 31;
        int octile = page >> 3, icc = page & 7;
        int oc = octile * 32 + ocl, ic = icc * 32 + icl;
        float a = w1[((size_t)oc * CIN + ic) * 9 + tap];
        unsigned short hi = f2bf(a);
        outv = (term == 0) ? (short)hi : (short)f2bf(a - bf2f(hi));
    }
    wpk[e] = outv;
}

// ---------------------------------------------------------------------------
// conv1 via MFMA implicit GEMM, 2-term bf16 split (4 products).
// Block: 32 oc x (8 rows x 16 cols) pixel tile.  Grid (800 px-tiles, 12 octiles).
// Per 32-ic chunk: ONE staging round serves all 9 taps:
//   - Bhalo[10*18 halo px][t0 icl32|t1 icl32|pad] : tap = shifted LDS row
//   - A[9 taps][32 ocl][t0|t1|pad]                : flat copy from wpk
// -> 2 barriers per ic-chunk (16 per block, was 144), 144 MFMA/wave between.
// Fragment k-layout identical to the round-5-verified kernel.
// ---------------------------------------------------------------------------
__global__ __launch_bounds__(256, 2) void conv1_mfma(
    const float* __restrict__ feat, const short* __restrict__ wpk,
    const float* __restrict__ b1, const float* __restrict__ gamma,
    const float* __restrict__ beta, const float* __restrict__ mean,
    const float* __restrict__ var, float* __restrict__ y1) {
    const int tile = blockIdx.x;            // 0..799
    const int bb = tile / 200, tt = tile % 200;
    const int ty = (tt / 10) * 8, tx = (tt % 10) * 16;
    const int octile = blockIdx.y;          // 0..11
    const int oc0 = octile * 32;
    const int tid  = threadIdx.x;
    const int w    = tid >> 6;              // wave 0..3 -> ni pair w*2, w*2+1
    const int lane = tid & 63;
    const int quad = lane >> 4;
    const int l15  = lane & 15;

    __shared__ short Alds[288 * 68];        // [tap*32+ocl][t0|t1|pad] 39168 B
    __shared__ short Blds[180 * 68];        // [hy*18+hx ][t0|t1|pad] 24480 B

    f32x4 acc[2][2];
#pragma unroll
    for (int mi = 0; mi < 2; ++mi)
#pragma unroll
        for (int nj = 0; nj < 2; ++nj) acc[mi][nj] = (f32x4){0.f, 0.f, 0.f, 0.f};

    const int4v* asrc_base = (const int4v*)wpk + (size_t)(octile * 8) * 2448;
    unsigned* Bd = (unsigned*)Blds;

    for (int icc = 0; icc < 8; ++icc) {
        __syncthreads();                    // protect prev chunk's frag reads
        // ---- stage A: 9 taps x 32 ocl, flat copy of 2448 int4 (39168 B)
        {
            const int4v* asrc = asrc_base + (size_t)icc * 2448;
            int4v* adst = (int4v*)Alds;
#pragma unroll
            for (int i = 0; i < 10; ++i) {
                int idx = tid + i * 256;
                if (idx < 2448) adst[idx] = asrc[idx];
            }
        }
        // ---- stage B halo: 180 positions x 32 ic (2 ic per thread-iter)
        for (int i = tid; i < 2880; i += 256) {
            int icp = i / 180, hp = i - icp * 180;   // icp 0..15, hp 0..179
            int hy = hp / 18, hx = hp - hy * 18;
            int gy = ty + hy - 1, gx = tx + hx - 1;
            bool valid = ((unsigned)gy < IMG) && ((unsigned)gx < IMG);
            const float* fs = feat + ((size_t)(bb * CIN + icc * 32 + icp * 2)) * HWSZ
                                   + (valid ? (gy * IMG + gx) : 0);
            float v0 = valid ? fs[0]    : 0.0f;
            float v1 = valid ? fs[HWSZ] : 0.0f;
            unsigned short h0 = f2bf(v0), h1 = f2bf(v1);
            unsigned short m0 = f2bf(v0 - bf2f(h0)), m1 = f2bf(v1 - bf2f(h1));
            Bd[hp * 34 + icp]      = (unsigned)h0 | ((unsigned)h1 << 16);
            Bd[hp * 34 + 16 + icp] = (unsigned)m0 | ((unsigned)m1 << 16);
        }
        __syncthreads();

#pragma unroll
        for (int tap = 0; tap < 9; ++tap) {
            const int sy = tap / 3, sx = tap % 3;   // halo shift (dy+1, dx+1)
            frag_u Af[2][2], Bf[2][2];
#pragma unroll
            for (int t = 0; t < 2; ++t) {
#pragma unroll
                for (int mi = 0; mi < 2; ++mi) {
                    int off = (tap * 32 + mi * 16 + l15) * 68 + t * 32 + quad * 8;
                    Af[t][mi].u[0] = *(const u64*)&Alds[off];
                    Af[t][mi].u[1] = *(const u64*)&Alds[off + 4];
                }
#pragma unroll
                for (int nj = 0; nj < 2; ++nj) {
                    int hy = w * 2 + nj + sy, hx = l15 + sx;
                    int off = (hy * 18 + hx) * 68 + t * 32 + quad * 8;
                    Bf[t][nj].u[0] = *(const u64*)&Blds[off];
                    Bf[t][nj].u[1] = *(const u64*)&Blds[off + 4];
                }
            }
#pragma unroll
            for (int mi = 0; mi < 2; ++mi)
#pragma unroll
                for (int nj = 0; nj < 2; ++nj) {
                    acc[mi][nj] = __builtin_amdgcn_mfma_f32_16x16x32_bf16(
                        Af[0][mi].s8, Bf[0][nj].s8, acc[mi][nj], 0, 0, 0);
                    acc[mi][nj] = __builtin_amdgcn_mfma_f32_16x16x32_bf16(
                        Af[0][mi].s8, Bf[1][nj].s8, acc[mi][nj], 0, 0, 0);
                    acc[mi][nj] = __builtin_amdgcn_mfma_f32_16x16x32_bf16(
                        Af[1][mi].s8, Bf[0][nj].s8, acc[mi][nj], 0, 0, 0);
                    acc[mi][nj] = __builtin_amdgcn_mfma_f32_16x16x32_bf16(
                        Af[1][mi].s8, Bf[1][nj].s8, acc[mi][nj], 0, 0, 0);
                }
        }
    }

    // ---- epilogue: BN + ReLU.  C/D: col(l15)=px-in-row, row(quad*4+r)=oc.
#pragma unroll
    for (int nj = 0; nj < 2; ++nj) {
        const int py = w * 2 + nj;
        const int gy = ty + py, gx = tx + l15;
#pragma unroll
        for (int mi = 0; mi < 2; ++mi)
#pragma unroll
            for (int r = 0; r < 4; ++r) {
                const int oc = oc0 + mi * 16 + quad * 4 + r;
                float v = acc[mi][nj][r] + b1[oc];
                v = (v - mean[oc]) * (gamma[oc] / sqrtf(var[oc] + 1e-5f)) + beta[oc];
                y1[((size_t)(bb * COUT1 + oc)) * HWSZ + gy * IMG + gx] = fmaxf(v, 0.0f);
            }
    }
}

// ---------------------------------------------------------------------------
// conv2: grouped 3x3, only the SEL channels; sigmoid where needed; -> d_out.
// ---------------------------------------------------------------------------
__global__ __launch_bounds__(256, 2) void conv2_kernel(
    const float* __restrict__ y1, const float* __restrict__ w2,
    const float* __restrict__ b2, float* __restrict__ out) {
    const int KH[6]   = {1, 1, 2, 1, 2, 4};
    const int REG[6]  = {OFF_LMAP, OFF_JMAP, OFF_JOFF, OFF_CMAP, OFF_COFF, OFF_LVEC};
    const int SIGF[6] = {1, 1, 0, 1, 0, 0};

    const int bz = blockIdx.z;
    const int b  = bz / 6;
    const int h  = bz % 6;
    const int k  = KH[h];
    const int tx = blockIdx.x * 16, ty = blockIdx.y * 16;
    const int lx = threadIdx.x, ly = threadIdx.y;
    const int tid = ly * 16 + lx;

    __shared__ float tin[4][18][33];
    float acc[4] = {0.0f, 0.0f, 0.0f, 0.0f};

    const float* yb = y1 + ((size_t)(b * COUT1 + h * 64)) * HWSZ;

    for (int ic0 = 0; ic0 < 64; ic0 += 4) {
        for (int i = tid; i < 1296; i += 256) {
            int c = i / 324, rem = i - c * 324;
            int r = rem / 18, col = rem - r * 18;
            int gy = ty - 1 + r, gx = tx - 1 + col;
            float v = 0.0f;
            if (gy >= 0 && gy < IMG && gx >= 0 && gx < IMG)
                v = yb[(size_t)(ic0 + c) * HWSZ + gy * IMG + gx];
            tin[c][r][col] = v;
        }
        __syncthreads();
#pragma unroll
        for (int c = 0; c < 4; ++c) {
            float n0 = tin[c][ly][lx],     n1 = tin[c][ly][lx + 1],     n2 = tin[c][ly][lx + 2];
            float n3 = tin[c][ly + 1][lx], n4 = tin[c][ly + 1][lx + 1], n5 = tin[c][ly + 1][lx + 2];
            float n6 = tin[c][ly + 2][lx], n7 = tin[c][ly + 2][lx + 1], n8 = tin[c][ly + 2][lx + 2];
#pragma unroll
            for (int o = 0; o < 4; ++o) {
                if (o < k) {
                    const float* wp = w2 + ((size_t)((h * 4 + o) * 64 + (ic0 + c))) * 9;
                    acc[o] = fmaf(n0, wp[0], fmaf(n1, wp[1], fmaf(n2, wp[2],
                             fmaf(n3, wp[3], fmaf(n4, wp[4], fmaf(n5, wp[5],
                             fmaf(n6, wp[6], fmaf(n7, wp[7], fmaf(n8, wp[8], acc[o])))))))));
                }
            }
        }
        __syncthreads();
    }

    const int p = (ty + ly) * IMG + tx + lx;
    for (int o = 0; o < k; ++o) {
        float v = acc[o] + b2[h * 4 + o];
        if (SIGF[h]) v = sigmoidf(v);
        out[REG[h] + ((size_t)(b * k + o)) * HWSZ + p] = v;
    }
}

// ---------------------------------------------------------------------------
// NMS on jmap + pack sort keys (value_bits<<32 | ~index  == lax.top_k order).
// ---------------------------------------------------------------------------
__global__ void nms_pack_kernel(const float* __restrict__ out,
                                u64* __restrict__ jsort,
                                u64* __restrict__ csort) {
    const int g = blockIdx.x;           // 0..399
    const int b = g / 100, q = g % 100;
    const int p = q * 256 + threadIdx.x;
    const float* jm = out + OFF_JMAP + (size_t)b * HWSZ;
    const float* cm = out + OFF_CMAP + (size_t)b * HWSZ;

    const int x = p % IMG, y = p / IMG;
    float v = jm[p];
    float mx = v;
#pragma unroll
    for (int dy = -1; dy <= 1; ++dy)
#pragma unroll
        for (int dx = -1; dx <= 1; ++dx) {
            int nx = x + dx, ny = y + dy;
            if (nx >= 0 && nx < IMG && ny >= 0 && ny < IMG)
                mx = fmaxf(mx, jm[ny * IMG + nx]);
        }
    float nmsv = (v == mx) ? v : 0.0f;

    u64 tagj = ((u64)__float_as_uint(nmsv) << 32)
             | (u64)(0xFFFFFFFFu - (unsigned)p);
    u64 tagc = ((u64)__float_as_uint(cm[p]) << 32)
             | (u64)(0xFFFFFFFFu - (unsigned)p);
    jsort[(size_t)b * 32768 + p] = tagj;
    csort[(size_t)b * 32768 + p] = tagc;
    if (q < 28) {                        // pad 25600..32767 with minimal keys
        int pp = 25600 + q * 256 + threadIdx.x;
        jsort[(size_t)b * 32768 + pp] = 0ull;
        csort[(size_t)b * 32768 + pp] = 0ull;
    }
}

// ---------------------------------------------------------------------------
// Hybrid bitonic sort, descending, 8 arrays x 32768 u64.
// ---------------------------------------------------------------------------
__global__ __launch_bounds__(1024) void sort64_ldsA(u64* __restrict__ buf) {
    __shared__ u64 s[8192];
    const size_t base = (size_t)blockIdx.x * 8192;   // 32 chunks (8 arrays x 4)
    const int cbase = (blockIdx.x & 3) * 8192;       // chunk offset within array
    for (int i = threadIdx.x; i < 8192; i += 1024) s[i] = buf[base + i];
    for (int k = 2; k <= 8192; k <<= 1)
        for (int j = k >> 1; j > 0; j >>= 1) {
            __syncthreads();
            for (int t = threadIdx.x; t < 4096; t += 1024) {
                int i = ((t & ~(j - 1)) << 1) | (t & (j - 1));
                int l = i | j;
                bool desc = (((i + cbase) & k) == 0);
                u64 x = s[i], y = s[l];
                if (desc ? (x < y) : (x > y)) { s[i] = y; s[l] = x; }
            }
        }
    __syncthreads();
    for (int i = threadIdx.x; i < 8192; i += 1024) buf[base + i] = s[i];
}

__global__ void sort64_gstep(u64* __restrict__ buf, int k, int j) {
    int t = blockIdx.x * 256 + threadIdx.x;          // 8 arrays * 16384 pairs
    int arr = t >> 14, p = t & 16383;
    int i = ((p & ~(j - 1)) << 1) | (p & (j - 1));
    int l = i | j;
    bool desc = ((i & k) == 0);
    u64* a = buf + (size_t)arr * 32768;
    u64 x = a[i], y = a[l];
    if (desc ? (x < y) : (x > y)) { a[i] = y; a[l] = x; }
}

__global__ __launch_bounds__(1024) void sort64_ldsB(u64* __restrict__ buf, int k) {
    __shared__ u64 s[8192];
    const size_t base = (size_t)blockIdx.x * 8192;
    const int cbase = (blockIdx.x & 3) * 8192;
    for (int i = threadIdx.x; i < 8192; i += 1024) s[i] = buf[base + i];
    for (int j = 4096; j > 0; j >>= 1) {
        __syncthreads();
        for (int t = threadIdx.x; t < 4096; t += 1024) {
            int i = ((t & ~(j - 1)) << 1) | (t & (j - 1));
            int l = i | j;
            bool desc = (((i + cbase) & k) == 0);
            u64 x = s[i], y = s[l];
            if (desc ? (x < y) : (x > y)) { s[i] = y; s[l] = x; }
        }
    }
    __syncthreads();
    for (int i = threadIdx.x; i < 8192; i += 1024) buf[base + i] = s[i];
}

// Full-LDS bitonic sort, ascending, 8192 int keys (one array per block).
__global__ __launch_bounds__(1024) void sort32_lds(int* __restrict__ buf) {
    __shared__ int s[8192];
    int* a = buf + (size_t)blockIdx.x * 8192;
    for (int i = threadIdx.x; i < 8192; i += 1024) s[i] = a[i];
    for (int k = 2; k <= 8192; k <<= 1)
        for (int j = k >> 1; j > 0; j >>= 1) {
            __syncthreads();
            for (int t = threadIdx.x; t < 4096; t += 1024) {
                int i = ((t & ~(j - 1)) << 1) | (t & (j - 1));
                int l = i | j;
                bool asc = ((i & k) == 0);
                int x = s[i], y = s[l];
                if (asc ? (x > y) : (x < y)) { s[i] = y; s[l] = x; }
            }
        }
    __syncthreads();
    for (int i = threadIdx.x; i < 8192; i += 1024) a[i] = s[i];
}

// Top-300 junctions: coordinates + validity.
__global__ void junction_kernel(const u64* __restrict__ jsort,
                                const float* __restrict__ out,
                                float* __restrict__ junc, int* __restrict__ jvalid) {
    const int b = blockIdx.x;
    const int t = threadIdx.x;
    if (t >= 300) return;
    u64 key = jsort[(size_t)b * 32768 + t];
    float score  = __uint_as_float((unsigned)(key >> 32));
    unsigned idx = 0xFFFFFFFFu - (unsigned)(key & 0xFFFFFFFFull);
    const float* j0 = out + OFF_JOFF + (size_t)(b * 2) * HWSZ;
    const float* j1 = j0 + HWSZ;
    float jx = (float)(idx % IMG) + j0[idx] + 0.5f;
    float jy = (float)(idx / IMG) + j1[idx] + 0.5f;
    junc[(size_t)(b * 300 + t) * 2]     = clip_coord(jx);
    junc[(size_t)(b * 300 + t) * 2 + 1] = clip_coord(jy);
    jvalid[b * 300 + t] = (score >= 0.008f) ? 1 : 0;
}

// Top-5000 centers -> line endpoints -> nearest-junction keys.
__global__ void lines_kernel(const u64* __restrict__ csort,
                             const float* __restrict__ junc,
                             const int* __restrict__ jvalid,
                             const float* __restrict__ out,
                             int* __restrict__ lkeys) {
    const int b = blockIdx.y;
    const int t = blockIdx.x * 256 + threadIdx.x;

    __shared__ float jx[300], jy[300];
    __shared__ int jv[300];
    for (int i = threadIdx.x; i < 300; i += 256) {
        jx[i] = junc[(size_t)(b * 300 + i) * 2];
        jy[i] = junc[(size_t)(b * 300 + i) * 2 + 1];
        jv[i] = jvalid[b * 300 + i];
    }
    __syncthreads();

    if (t >= 8192) return;
    if (t >= 5000) { lkeys[b * 8192 + t] = 0x7FFFFFFF; return; }

    u64 key = csort[(size_t)b * 32768 + t];
    unsigned idx = 0xFFFFFFFFu - (unsigned)(key & 0xFFFFFFFFull);
    const float* c0 = out + OFF_COFF + (size_t)(b * 2) * HWSZ;
    const float* c1 = c0 + HWSZ;
    const float* lv = out + OFF_LVEC + (size_t)(b * 4) * HWSZ;

    float cx = (float)(idx % IMG) + c0[idx] + 0.5f;
    float cy = (float)(idx / IMG) + c1[idx] + 0.5f;
    float e0x = clip_coord(cx + lv[idx]);
    float e0y = clip_coord(cy + lv[HWSZ + idx]);
    float e1x = clip_coord(cx + lv[2 * HWSZ + idx]);
    float e1y = clip_coord(cy + lv[3 * HWSZ + idx]);

    float m1 = 1e18f, m2 = 1e18f;
    int i1 = 0, i2 = 0;
    for (int j = 0; j < 300; ++j) {
        if (jv[j]) {
            float dx = e0x - jx[j], dy = e0y - jy[j];
            float d = dx * dx + dy * dy;
            if (d < m1) { m1 = d; i1 = j; }
            dx = e1x - jx[j]; dy = e1y - jy[j];
            d = dx * dx + dy * dy;
            if (d < m2) { m2 = d; i2 = j; }
        }
    }
    int imin = min(i1, i2), imax = max(i1, i2);
    lkeys[b * 8192 + t] = (i1 != i2) ? (imin * 300 + imax) : BIGK;
}

// Dedup sorted keys -> line segments + mask.
__global__ void finalize_kernel(const int* __restrict__ lkeys,
                                const float* __restrict__ junc,
                                float* __restrict__ out) {
    const int b = blockIdx.y;
    const int t = blockIdx.x * 256 + threadIdx.x;
    if (t >= 5000) return;
    const int* lk = lkeys + b * 8192;
    int sk = lk[t];
    bool first = ((t == 0) || (sk != lk[t - 1])) && (sk < BIGK);
    int a  = first ? sk / 300 : 0;
    int bb = first ? sk % 300 : 0;
    float p0x = junc[(size_t)(b * 300 + a) * 2];
    float p0y = junc[(size_t)(b * 300 + a) * 2 + 1];
    float p1x = junc[(size_t)(b * 300 + bb) * 2];
    float p1y = junc[(size_t)(b * 300 + bb) * 2 + 1];
    if (p0y > p1y) {
        float tx = p0x; p0x = p1x; p1x = tx;
        float ty = p0y; p0y = p1y; p1y = ty;
    }
    size_t base = OFF_LOI + (size_t)(b * 5000 + t) * 4;
    out[base]     = p0x;
    out[base + 1] = p0y;
    out[base + 2] = p1x;
    out[base + 3] = p1y;
    out[OFF_MASK + b * 5000 + t] = first ? 1.0f : 0.0f;
}

extern "C" void kernel_launch(void* const* d_in, const int* in_sizes, int n_in,
                              void* d_out, int out_size, void* d_ws, size_t ws_size,
                              hipStream_t stream) {
    const float* feat  = (const float*)d_in[0];
    const float* w1    = (const float*)d_in[1];
    const float* b1    = (const float*)d_in[2];
    const float* gamma = (const float*)d_in[3];
    const float* beta  = (const float*)d_in[4];
    const float* mean  = (const float*)d_in[5];
    const float* var   = (const float*)d_in[6];
    const float* w2    = (const float*)d_in[7];
    const float* b2    = (const float*)d_in[8];
    float* out = (float*)d_out;
    char*  ws  = (char*)d_ws;

    if (ws_size < WS_NEED) return;   // ~163 MB needed

    float* y1 = (float*)(ws + WS_Y1);
    u64* jsort = (u64*)(ws + WS_JSORT);
    float* junc = (float*)(ws + WS_JUNC);
    int* jvalid = (int*)(ws + WS_JVAL);
    int* lkeys  = (int*)(ws + WS_LKEY);
    u64* csort = (u64*)(ws + WS_CSORT);
    short* wpk = (short*)(ws + WS_WPK);

    // 0. pre-split/pack conv1 weights into MFMA staging layout
    wpack_kernel<<<dim3(7344), dim3(256), 0, stream>>>(w1, wpk);

    // 1. conv1 + BN + ReLU -> y1  (MFMA implicit GEMM, 32oc x 8x16px blocks)
    conv1_mfma<<<dim3(800, 12), dim3(256), 0, stream>>>(
        feat, wpk, b1, gamma, beta, mean, var, y1);

    // 2. conv2 (grouped, SEL channels only) -> maps in d_out
    conv2_kernel<<<dim3(10, 10, NB * 6), dim3(16, 16), 0, stream>>>(y1, w2, b2, out);

    // 3. NMS + pack sort keys
    nms_pack_kernel<<<dim3(NB * 100), dim3(256), 0, stream>>>(out, jsort, csort);

    // 4. hybrid bitonic sort of 8 u64 arrays (4 jmap + 4 cmap, contiguous)
    sort64_ldsA<<<dim3(32), dim3(1024), 0, stream>>>(jsort);
    sort64_gstep<<<dim3(512), dim3(256), 0, stream>>>(jsort, 16384, 8192);
    sort64_ldsB<<<dim3(32), dim3(1024), 0, stream>>>(jsort, 16384);
    sort64_gstep<<<dim3(512), dim3(256), 0, stream>>>(jsort, 32768, 16384);
    sort64_gstep<<<dim3(512), dim3(256), 0, stream>>>(jsort, 32768, 8192);
    sort64_ldsB<<<dim3(32), dim3(1024), 0, stream>>>(jsort, 32768);

    // 5. junctions
    junction_kernel<<<dim3(NB), dim3(320), 0, stream>>>(jsort, out, junc, jvalid);

    // 6. line keys
    lines_kernel<<<dim3(32, NB), dim3(256), 0, stream>>>(csort, junc, jvalid, out, lkeys);

    // 7. sort line keys ascending (full LDS)
    sort32_lds<<<dim3(NB), dim3(1024), 0, stream>>>(lkeys);

    // 8. dedup + emit loi/mask
    finalize_kernel<<<dim3(20, NB), dim3(256), 0, stream>>>(lkeys, junc, out);
}

// Round 7
// 1656.809 us; speedup vs baseline: 3.3630x; 1.1287x over previous
//
#include <hip/hip_runtime.h>
#include <math.h>

#define IMG   160
#define HWSZ  25600
#define NB    4
#define CIN   256
#define COUT1 384
#define BIGK  90000

// output offsets (in floats)
#define OFF_LMAP 0
#define OFF_JMAP 102400
#define OFF_JOFF 204800
#define OFF_CMAP 409600
#define OFF_COFF 512000
#define OFF_LVEC 716800
#define OFF_LOI  1126400
#define OFF_MASK 1206400

// workspace offsets (bytes)
static const size_t WS_Y1    = 0;
static const size_t WS_JSORT = (size_t)NB * COUT1 * HWSZ * 4;            // 157286400
static const size_t WS_CSORT = WS_JSORT + (size_t)NB * 32768 * 8;
static const size_t WS_JUNC  = WS_CSORT + (size_t)NB * 32768 * 8;
static const size_t WS_JVAL  = WS_JUNC + (size_t)NB * 300 * 2 * 4;
static const size_t WS_LKEY  = WS_JVAL + (size_t)NB * 300 * 4;
static const size_t WS_WPK   = WS_LKEY + (size_t)NB * 8192 * 4;
// Wpack: 12 octiles * 8 icc * 9 taps * 32 ocl * 64 shorts * 2 B = 3,538,944
static const size_t WS_NEED  = WS_WPK + (size_t)12 * 8 * 9 * 32 * 64 * 2;

typedef unsigned long long u64;
typedef __attribute__((ext_vector_type(8))) short short8;
typedef __attribute__((ext_vector_type(4))) float f32x4;
typedef __attribute__((ext_vector_type(4))) int int4v;

union frag_u { short8 s8; u64 u[2]; };

__device__ __forceinline__ float clip_coord(float v) {
    return fminf(fmaxf(v, 0.0f), 159.9999f);
}
__device__ __forceinline__ float sigmoidf(float v) {
    return 1.0f / (1.0f + expf(-v));
}
__device__ __forceinline__ unsigned short f2bf(float f) {   // RNE
    unsigned u = __float_as_uint(f);
    return (unsigned short)((u + 0x7FFFu + ((u >> 16) & 1u)) >> 16);
}
__device__ __forceinline__ float bf2f(unsigned short h) {
    return __uint_as_float((unsigned)h << 16);
}

// ---------------------------------------------------------------------------
// Pre-pack w1 into the LDS image consumed by conv1_mfma:
//   Wpack[octile 12][icc 8][tap 9][ocl 32][64 shorts, slot-permuted, NO pad]
// Row = 16 slots of 8 B.  Logical slot s = t*8 + quad*2 + h holds shorts
// (t*32 + quad*8 + h*4 .. +3); physical slot p = s ^ (ocl & 15) (bank spread
// without padding).  term0 = bf16_rne(w), term1 = bf16_rne(w - term0).
// ---------------------------------------------------------------------------
__global__ void wpack_kernel(const float* __restrict__ w1, short* __restrict__ wpk) {
    int e = blockIdx.x * 256 + threadIdx.x;      // 12*8*9*32*64 = 1,769,472 exact
    int row = e >> 6, sp = e & 63;
    int ocl = row & 31;
    int tap = (row >> 5) % 9;
    int icc = (row / 288) & 7;
    int octile = row / 2304;
    int s = (sp >> 2) ^ (ocl & 15);              // logical slot
    int ql = s * 4 + (sp & 3);                   // logical short index 0..63
    int term = ql >> 5, icl = ql & 31;
    int oc = octile * 32 + ocl, ic = icc * 32 + icl;
    float a = w1[((size_t)oc * CIN + ic) * 9 + tap];
    unsigned short hi = f2bf(a);
    wpk[e] = (term == 0) ? (short)hi : (short)f2bf(a - bf2f(hi));
}

// ---------------------------------------------------------------------------
// conv1 via MFMA implicit GEMM, 2-term bf16 split (4 products).
// Block: 32 oc x (16 rows x 16 cols) px tile.  Grid (400 px-tiles, 12 octiles).
// Wave w: px rows w*4..w*4+3 (Nj=4) x 32 oc (Mi=2) -> 32 MFMA per tap,
// 12 frag loads per tap (0.375 KB LDS read / MFMA -> MFMA-bound).
// LDS: A pad-free stride-64 + XOR slot perm (baked in wpk); B halo stride 68.
// Total 80928 B -> 2 blocks/CU.  Accumulation order bitwise == round 6.
// ---------------------------------------------------------------------------
__global__ __launch_bounds__(256, 2) void conv1_mfma(
    const float* __restrict__ feat, const short* __restrict__ wpk,
    const float* __restrict__ b1, const float* __restrict__ gamma,
    const float* __restrict__ beta, const float* __restrict__ mean,
    const float* __restrict__ var, float* __restrict__ y1) {
    const int tile = blockIdx.x;            // 0..399
    const int bb = tile / 100, tt = tile % 100;
    const int ty = (tt / 10) * 16, tx = (tt % 10) * 16;
    const int octile = blockIdx.y;          // 0..11
    const int oc0 = octile * 32;
    const int tid  = threadIdx.x;
    const int w    = tid >> 6;              // wave: px rows w*4..w*4+3
    const int lane = tid & 63;
    const int quad = lane >> 4;
    const int l15  = lane & 15;

    __shared__ short Alds[288 * 64];        // [tap*32+ocl][64 sh, perm'd] 36864 B
    __shared__ short Blds[324 * 68];        // [hy*18+hx][t0 32|t1 32|pad] 44064 B

    // A frag lane byte-offsets: row l15 (within 16-row tile), phys slot
    // (t*8+quad*2+h) ^ l15
    int aoff[2][2];
#pragma unroll
    for (int t = 0; t < 2; ++t)
#pragma unroll
        for (int h = 0; h < 2; ++h)
            aoff[t][h] = l15 * 128 + (((t * 8 + quad * 2 + h) ^ l15) * 8);

    f32x4 acc[2][4];
#pragma unroll
    for (int mi = 0; mi < 2; ++mi)
#pragma unroll
        for (int nj = 0; nj < 4; ++nj) acc[mi][nj] = (f32x4){0.f, 0.f, 0.f, 0.f};

    const int4v* asrc_base = (const int4v*)wpk + (size_t)(octile * 8) * 2304;
    unsigned* Bd = (unsigned*)Blds;

    for (int icc = 0; icc < 8; ++icc) {
        __syncthreads();                    // protect prev chunk's frag reads
        // ---- stage A: 36864 B = 2304 int4, exactly 9 full iters
        {
            const int4v* asrc = asrc_base + (size_t)icc * 2304;
            int4v* adst = (int4v*)Alds;
#pragma unroll
            for (int i = 0; i < 9; ++i)
                adst[tid + i * 256] = asrc[tid + i * 256];
        }
        // ---- stage B halo: 324 positions x 32 ic (2 ic per iter)
        for (int i = tid; i < 5184; i += 256) {
            int icp = i / 324, hp = i - icp * 324;   // icp 0..15
            int hy = hp / 18, hx = hp - hy * 18;
            int gy = ty + hy - 1, gx = tx + hx - 1;
            bool valid = ((unsigned)gy < IMG) && ((unsigned)gx < IMG);
            const float* fs = feat + ((size_t)(bb * CIN + icc * 32 + icp * 2)) * HWSZ
                                   + (valid ? (gy * IMG + gx) : 0);
            float v0 = valid ? fs[0]    : 0.0f;
            float v1 = valid ? fs[HWSZ] : 0.0f;
            unsigned short h0 = f2bf(v0), h1 = f2bf(v1);
            unsigned short m0 = f2bf(v0 - bf2f(h0)), m1 = f2bf(v1 - bf2f(h1));
            Bd[hp * 34 + icp]      = (unsigned)h0 | ((unsigned)h1 << 16);
            Bd[hp * 34 + 16 + icp] = (unsigned)m0 | ((unsigned)m1 << 16);
        }
        __syncthreads();

#pragma unroll
        for (int tap = 0; tap < 9; ++tap) {
            const int sy = tap / 3, sx = tap % 3;
            frag_u Af[2][2], Bf[2][4];
#pragma unroll
            for (int t = 0; t < 2; ++t) {
#pragma unroll
                for (int mi = 0; mi < 2; ++mi) {
                    const char* base = (const char*)Alds + (tap * 32 + mi * 16) * 128;
                    Af[t][mi].u[0] = *(const u64*)(base + aoff[t][0]);
                    Af[t][mi].u[1] = *(const u64*)(base + aoff[t][1]);
                }
#pragma unroll
                for (int nj = 0; nj < 4; ++nj) {
                    int pos = (w * 4 + nj + sy) * 18 + (l15 + sx);
                    const short* bp = &Blds[pos * 68 + t * 32 + quad * 8];
                    Bf[t][nj].u[0] = *(const u64*)bp;
                    Bf[t][nj].u[1] = *(const u64*)(bp + 4);
                }
            }
#pragma unroll
            for (int mi = 0; mi < 2; ++mi)
#pragma unroll
                for (int nj = 0; nj < 4; ++nj) {
                    acc[mi][nj] = __builtin_amdgcn_mfma_f32_16x16x32_bf16(
                        Af[0][mi].s8, Bf[0][nj].s8, acc[mi][nj], 0, 0, 0);
                    acc[mi][nj] = __builtin_amdgcn_mfma_f32_16x16x32_bf16(
                        Af[0][mi].s8, Bf[1][nj].s8, acc[mi][nj], 0, 0, 0);
                    acc[mi][nj] = __builtin_amdgcn_mfma_f32_16x16x32_bf16(
                        Af[1][mi].s8, Bf[0][nj].s8, acc[mi][nj], 0, 0, 0);
                    acc[mi][nj] = __builtin_amdgcn_mfma_f32_16x16x32_bf16(
                        Af[1][mi].s8, Bf[1][nj].s8, acc[mi][nj], 0, 0, 0);
                }
        }
    }

    // ---- epilogue: BN + ReLU.  C/D: col(l15)=px col, row(quad*4+r)=oc.
#pragma unroll
    for (int nj = 0; nj < 4; ++nj) {
        const int gy = ty + w * 4 + nj, gx = tx + l15;
#pragma unroll
        for (int mi = 0; mi < 2; ++mi)
#pragma unroll
            for (int r = 0; r < 4; ++r) {
                const int oc = oc0 + mi * 16 + quad * 4 + r;
                float v = acc[mi][nj][r] + b1[oc];
                v = (v - mean[oc]) * (gamma[oc] / sqrtf(var[oc] + 1e-5f)) + beta[oc];
                y1[((size_t)(bb * COUT1 + oc)) * HWSZ + gy * IMG + gx] = fmaxf(v, 0.0f);
            }
    }
}

// ---------------------------------------------------------------------------
// conv2: grouped 3x3, only the SEL channels; sigmoid where needed; -> d_out.
// 16-ic LDS chunks (4 barrier rounds instead of 16).
// ---------------------------------------------------------------------------
__global__ __launch_bounds__(256, 2) void conv2_kernel(
    const float* __restrict__ y1, const float* __restrict__ w2,
    const float* __restrict__ b2, float* __restrict__ out) {
    const int KH[6]   = {1, 1, 2, 1, 2, 4};
    const int REG[6]  = {OFF_LMAP, OFF_JMAP, OFF_JOFF, OFF_CMAP, OFF_COFF, OFF_LVEC};
    const int SIGF[6] = {1, 1, 0, 1, 0, 0};

    const int bz = blockIdx.z;
    const int b  = bz / 6;
    const int h  = bz % 6;
    const int k  = KH[h];
    const int tx = blockIdx.x * 16, ty = blockIdx.y * 16;
    const int lx = threadIdx.x, ly = threadIdx.y;
    const int tid = ly * 16 + lx;

    __shared__ float tin[16][18][33];
    float acc[4] = {0.0f, 0.0f, 0.0f, 0.0f};

    const float* yb = y1 + ((size_t)(b * COUT1 + h * 64)) * HWSZ;

    for (int ic0 = 0; ic0 < 64; ic0 += 16) {
        __syncthreads();
        for (int i = tid; i < 5184; i += 256) {
            int c = i / 324, rem = i - c * 324;
            int r = rem / 18, col = rem - r * 18;
            int gy = ty - 1 + r, gx = tx - 1 + col;
            float v = 0.0f;
            if (gy >= 0 && gy < IMG && gx >= 0 && gx < IMG)
                v = yb[(size_t)(ic0 + c) * HWSZ + gy * IMG + gx];
            tin[c][r][col] = v;
        }
        __syncthreads();
#pragma unroll 4
        for (int c = 0; c < 16; ++c) {
            float n0 = tin[c][ly][lx],     n1 = tin[c][ly][lx + 1],     n2 = tin[c][ly][lx + 2];
            float n3 = tin[c][ly + 1][lx], n4 = tin[c][ly + 1][lx + 1], n5 = tin[c][ly + 1][lx + 2];
            float n6 = tin[c][ly + 2][lx], n7 = tin[c][ly + 2][lx + 1], n8 = tin[c][ly + 2][lx + 2];
#pragma unroll
            for (int o = 0; o < 4; ++o) {
                if (o < k) {
                    const float* wp = w2 + ((size_t)((h * 4 + o) * 64 + (ic0 + c))) * 9;
                    acc[o] = fmaf(n0, wp[0], fmaf(n1, wp[1], fmaf(n2, wp[2],
                             fmaf(n3, wp[3], fmaf(n4, wp[4], fmaf(n5, wp[5],
                             fmaf(n6, wp[6], fmaf(n7, wp[7], fmaf(n8, wp[8], acc[o])))))))));
                }
            }
        }
    }

    const int p = (ty + ly) * IMG + tx + lx;
    for (int o = 0; o < k; ++o) {
        float v = acc[o] + b2[h * 4 + o];
        if (SIGF[h]) v = sigmoidf(v);
        out[REG[h] + ((size_t)(b * k + o)) * HWSZ + p] = v;
    }
}

// ---------------------------------------------------------------------------
// NMS on jmap + pack sort keys (value_bits<<32 | ~index  == lax.top_k order).
// ---------------------------------------------------------------------------
__global__ void nms_pack_kernel(const float* __restrict__ out,
                                u64* __restrict__ jsort,
                                u64* __restrict__ csort) {
    const int g = blockIdx.x;           // 0..399
    const int b = g / 100, q = g % 100;
    const int p = q * 256 + threadIdx.x;
    const float* jm = out + OFF_JMAP + (size_t)b * HWSZ;
    const float* cm = out + OFF_CMAP + (size_t)b * HWSZ;

    const int x = p % IMG, y = p / IMG;
    float v = jm[p];
    float mx = v;
#pragma unroll
    for (int dy = -1; dy <= 1; ++dy)
#pragma unroll
        for (int dx = -1; dx <= 1; ++dx) {
            int nx = x + dx, ny = y + dy;
            if (nx >= 0 && nx < IMG && ny >= 0 && ny < IMG)
                mx = fmaxf(mx, jm[ny * IMG + nx]);
        }
    float nmsv = (v == mx) ? v : 0.0f;

    u64 tagj = ((u64)__float_as_uint(nmsv) << 32)
             | (u64)(0xFFFFFFFFu - (unsigned)p);
    u64 tagc = ((u64)__float_as_uint(cm[p]) << 32)
             | (u64)(0xFFFFFFFFu - (unsigned)p);
    jsort[(size_t)b * 32768 + p] = tagj;
    csort[(size_t)b * 32768 + p] = tagc;
    if (q < 28) {                        // pad 25600..32767 with minimal keys
        int pp = 25600 + q * 256 + threadIdx.x;
        jsort[(size_t)b * 32768 + pp] = 0ull;
        csort[(size_t)b * 32768 + pp] = 0ull;
    }
}

// ---------------------------------------------------------------------------
// Hybrid bitonic sort, descending, 8 arrays x 32768 u64.
// ---------------------------------------------------------------------------
__global__ __launch_bounds__(1024) void sort64_ldsA(u64* __restrict__ buf) {
    __shared__ u64 s[8192];
    const size_t base = (size_t)blockIdx.x * 8192;   // 32 chunks (8 arrays x 4)
    const int cbase = (blockIdx.x & 3) * 8192;       // chunk offset within array
    for (int i = threadIdx.x; i < 8192; i += 1024) s[i] = buf[base + i];
    for (int k = 2; k <= 8192; k <<= 1)
        for (int j = k >> 1; j > 0; j >>= 1) {
            __syncthreads();
            for (int t = threadIdx.x; t < 4096; t += 1024) {
                int i = ((t & ~(j - 1)) << 1) | (t & (j - 1));
                int l = i | j;
                bool desc = (((i + cbase) & k) == 0);
                u64 x = s[i], y = s[l];
                if (desc ? (x < y) : (x > y)) { s[i] = y; s[l] = x; }
            }
        }
    __syncthreads();
    for (int i = threadIdx.x; i < 8192; i += 1024) buf[base + i] = s[i];
}

__global__ void sort64_gstep(u64* __restrict__ buf, int k, int j) {
    int t = blockIdx.x * 256 + threadIdx.x;          // 8 arrays * 16384 pairs
    int arr = t >> 14, p = t & 16383;
    int i = ((p & ~(j - 1)) << 1) | (p & (j - 1));
    int l = i | j;
    bool desc = ((i & k) == 0);
    u64* a = buf + (size_t)arr * 32768;
    u64 x = a[i], y = a[l];
    if (desc ? (x < y) : (x > y)) { a[i] = y; a[l] = x; }
}

__global__ __launch_bounds__(1024) void sort64_ldsB(u64* __restrict__ buf, int k) {
    __shared__ u64 s[8192];
    const size_t base = (size_t)blockIdx.x * 8192;
    const int cbase = (blockIdx.x & 3) * 8192;
    for (int i = threadIdx.x; i < 8192; i += 1024) s[i] = buf[base + i];
    for (int j = 4096; j > 0; j >>= 1) {
        __syncthreads();
        for (int t = threadIdx.x; t < 4096; t += 1024) {
            int i = ((t & ~(j - 1)) << 1) | (t & (j - 1));
            int l = i | j;
            bool desc = (((i + cbase) & k) == 0);
            u64 x = s[i], y = s[l];
            if (desc ? (x < y) : (x > y)) { s[i] = y; s[l] = x; }
        }
    }
    __syncthreads();
    for (int i = threadIdx.x; i < 8192; i += 1024) buf[base + i] = s[i];
}

// Full-LDS bitonic sort, ascending, 8192 int keys (one array per block).
__global__ __launch_bounds__(1024) void sort32_lds(int* __restrict__ buf) {
    __shared__ int s[8192];
    int* a = buf + (size_t)blockIdx.x * 8192;
    for (int i = threadIdx.x; i < 8192; i += 1024) s[i] = a[i];
    for (int k = 2; k <= 8192; k <<= 1)
        for (int j = k >> 1; j > 0; j >>= 1) {
            __syncthreads();
            for (int t = threadIdx.x; t < 4096; t += 1024) {
                int i = ((t & ~(j - 1)) << 1) | (t & (j - 1));
                int l = i | j;
                bool asc = ((i & k) == 0);
                int x = s[i], y = s[l];
                if (asc ? (x > y) : (x < y)) { s[i] = y; s[l] = x; }
            }
        }
    __syncthreads();
    for (int i = threadIdx.x; i < 8192; i += 1024) a[i] = s[i];
}

// Top-300 junctions: coordinates + validity.
__global__ void junction_kernel(const u64* __restrict__ jsort,
                                const float* __restrict__ out,
                                float* __restrict__ junc, int* __restrict__ jvalid) {
    const int b = blockIdx.x;
    const int t = threadIdx.x;
    if (t >= 300) return;
    u64 key = jsort[(size_t)b * 32768 + t];
    float score  = __uint_as_float((unsigned)(key >> 32));
    unsigned idx = 0xFFFFFFFFu - (unsigned)(key & 0xFFFFFFFFull);
    const float* j0 = out + OFF_JOFF + (size_t)(b * 2) * HWSZ;
    const float* j1 = j0 + HWSZ;
    float jx = (float)(idx % IMG) + j0[idx] + 0.5f;
    float jy = (float)(idx / IMG) + j1[idx] + 0.5f;
    junc[(size_t)(b * 300 + t) * 2]     = clip_coord(jx);
    junc[(size_t)(b * 300 + t) * 2 + 1] = clip_coord(jy);
    jvalid[b * 300 + t] = (score >= 0.008f) ? 1 : 0;
}

// Top-5000 centers -> line endpoints -> nearest-junction keys.
__global__ void lines_kernel(const u64* __restrict__ csort,
                             const float* __restrict__ junc,
                             const int* __restrict__ jvalid,
                             const float* __restrict__ out,
                             int* __restrict__ lkeys) {
    const int b = blockIdx.y;
    const int t = blockIdx.x * 256 + threadIdx.x;

    __shared__ float jx[300], jy[300];
    __shared__ int jv[300];
    for (int i = threadIdx.x; i < 300; i += 256) {
        jx[i] = junc[(size_t)(b * 300 + i) * 2];
        jy[i] = junc[(size_t)(b * 300 + i) * 2 + 1];
        jv[i] = jvalid[b * 300 + i];
    }
    __syncthreads();

    if (t >= 8192) return;
    if (t >= 5000) { lkeys[b * 8192 + t] = 0x7FFFFFFF; return; }

    u64 key = csort[(size_t)b * 32768 + t];
    unsigned idx = 0xFFFFFFFFu - (unsigned)(key & 0xFFFFFFFFull);
    const float* c0 = out + OFF_COFF + (size_t)(b * 2) * HWSZ;
    const float* c1 = c0 + HWSZ;
    const float* lv = out + OFF_LVEC + (size_t)(b * 4) * HWSZ;

    float cx = (float)(idx % IMG) + c0[idx] + 0.5f;
    float cy = (float)(idx / IMG) + c1[idx] + 0.5f;
    float e0x = clip_coord(cx + lv[idx]);
    float e0y = clip_coord(cy + lv[HWSZ + idx]);
    float e1x = clip_coord(cx + lv[2 * HWSZ + idx]);
    float e1y = clip_coord(cy + lv[3 * HWSZ + idx]);

    float m1 = 1e18f, m2 = 1e18f;
    int i1 = 0, i2 = 0;
    for (int j = 0; j < 300; ++j) {
        if (jv[j]) {
            float dx = e0x - jx[j], dy = e0y - jy[j];
            float d = dx * dx + dy * dy;
            if (d < m1) { m1 = d; i1 = j; }
            dx = e1x - jx[j]; dy = e1y - jy[j];
            d = dx * dx + dy * dy;
            if (d < m2) { m2 = d; i2 = j; }
        }
    }
    int imin = min(i1, i2), imax = max(i1, i2);
    lkeys[b * 8192 + t] = (i1 != i2) ? (imin * 300 + imax) : BIGK;
}

// Dedup sorted keys -> line segments + mask.
__global__ void finalize_kernel(const int* __restrict__ lkeys,
                                const float* __restrict__ junc,
                                float* __restrict__ out) {
    const int b = blockIdx.y;
    const int t = blockIdx.x * 256 + threadIdx.x;
    if (t >= 5000) return;
    const int* lk = lkeys + b * 8192;
    int sk = lk[t];
    bool first = ((t == 0) || (sk != lk[t - 1])) && (sk < BIGK);
    int a  = first ? sk / 300 : 0;
    int bb = first ? sk % 300 : 0;
    float p0x = junc[(size_t)(b * 300 + a) * 2];
    float p0y = junc[(size_t)(b * 300 + a) * 2 + 1];
    float p1x = junc[(size_t)(b * 300 + bb) * 2];
    float p1y = junc[(size_t)(b * 300 + bb) * 2 + 1];
    if (p0y > p1y) {
        float tx = p0x; p0x = p1x; p1x = tx;
        float ty = p0y; p0y = p1y; p1y = ty;
    }
    size_t base = OFF_LOI + (size_t)(b * 5000 + t) * 4;
    out[base]     = p0x;
    out[base + 1] = p0y;
    out[base + 2] = p1x;
    out[base + 3] = p1y;
    out[OFF_MASK + b * 5000 + t] = first ? 1.0f : 0.0f;
}

extern "C" void kernel_launch(void* const* d_in, const int* in_sizes, int n_in,
                              void* d_out, int out_size, void* d_ws, size_t ws_size,
                              hipStream_t stream) {
    const float* feat  = (const float*)d_in[0];
    const float* w1    = (const float*)d_in[1];
    const float* b1    = (const float*)d_in[2];
    const float* gamma = (const float*)d_in[3];
    const float* beta  = (const float*)d_in[4];
    const float* mean  = (const float*)d_in[5];
    const float* var   = (const float*)d_in[6];
    const float* w2    = (const float*)d_in[7];
    const float* b2    = (const float*)d_in[8];
    float* out = (float*)d_out;
    char*  ws  = (char*)d_ws;

    if (ws_size < WS_NEED) return;   // ~163 MB needed

    float* y1 = (float*)(ws + WS_Y1);
    u64* jsort = (u64*)(ws + WS_JSORT);
    float* junc = (float*)(ws + WS_JUNC);
    int* jvalid = (int*)(ws + WS_JVAL);
    int* lkeys  = (int*)(ws + WS_LKEY);
    u64* csort = (u64*)(ws + WS_CSORT);
    short* wpk = (short*)(ws + WS_WPK);

    // 0. pre-split/pack conv1 weights into MFMA staging layout (perm baked in)
    wpack_kernel<<<dim3(6912), dim3(256), 0, stream>>>(w1, wpk);

    // 1. conv1 + BN + ReLU -> y1  (MFMA implicit GEMM, 32oc x 16x16px blocks)
    conv1_mfma<<<dim3(400, 12), dim3(256), 0, stream>>>(
        feat, wpk, b1, gamma, beta, mean, var, y1);

    // 2. conv2 (grouped, SEL channels only) -> maps in d_out
    conv2_kernel<<<dim3(10, 10, NB * 6), dim3(16, 16), 0, stream>>>(y1, w2, b2, out);

    // 3. NMS + pack sort keys
    nms_pack_kernel<<<dim3(NB * 100), dim3(256), 0, stream>>>(out, jsort, csort);

    // 4. hybrid bitonic sort of 8 u64 arrays (4 jmap + 4 cmap, contiguous)
    sort64_ldsA<<<dim3(32), dim3(1024), 0, stream>>>(jsort);
    sort64_gstep<<<dim3(512), dim3(256), 0, stream>>>(jsort, 16384, 8192);
    sort64_ldsB<<<dim3(32), dim3(1024), 0, stream>>>(jsort, 16384);
    sort64_gstep<<<dim3(512), dim3(256), 0, stream>>>(jsort, 32768, 16384);
    sort64_gstep<<<dim3(512), dim3(256), 0, stream>>>(jsort, 32768, 8192);
    sort64_ldsB<<<dim3(32), dim3(1024), 0, stream>>>(jsort, 32768);

    // 5. junctions
    junction_kernel<<<dim3(NB), dim3(320), 0, stream>>>(jsort, out, junc, jvalid);

    // 6. line keys
    lines_kernel<<<dim3(32, NB), dim3(256), 0, stream>>>(csort, junc, jvalid, out, lkeys);

    // 7. sort line keys ascending (full LDS)
    sort32_lds<<<dim3(NB), dim3(1024), 0, stream>>>(lkeys);

    // 8. dedup + emit loi/mask
    finalize_kernel<<<dim3(20, NB), dim3(256), 0, stream>>>(lkeys, junc, out);
}

// Round 8
// 1366.090 us; speedup vs baseline: 4.0787x; 1.2128x over previous
//
#include <hip/hip_runtime.h>
#include <math.h>

#define IMG   160
#define HWSZ  25600
#define NB    4
#define CIN   256
#define COUT1 384
#define BIGK  90000

// output offsets (in floats)
#define OFF_LMAP 0
#define OFF_JMAP 102400
#define OFF_JOFF 204800
#define OFF_CMAP 409600
#define OFF_COFF 512000
#define OFF_LVEC 716800
#define OFF_LOI  1126400
#define OFF_MASK 1206400

// workspace offsets (bytes)
static const size_t WS_Y1    = 0;
static const size_t WS_JSORT = (size_t)NB * COUT1 * HWSZ * 4;            // 157286400
static const size_t WS_CSORT = WS_JSORT + (size_t)NB * 32768 * 8;
static const size_t WS_JUNC  = WS_CSORT + (size_t)NB * 32768 * 8;
static const size_t WS_JVAL  = WS_JUNC + (size_t)NB * 300 * 2 * 4;
static const size_t WS_LKEY  = WS_JVAL + (size_t)NB * 300 * 4;
static const size_t WS_WPK   = WS_LKEY + (size_t)NB * 8192 * 4;
// Wpack: 12 octiles * 8 icc * 9 taps * 32 ocl * 64 shorts * 2 B = 3,538,944
static const size_t WS_NEED  = WS_WPK + (size_t)12 * 8 * 9 * 32 * 64 * 2;

typedef unsigned long long u64;
typedef __attribute__((ext_vector_type(8))) short short8;
typedef __attribute__((ext_vector_type(4))) float f32x4;
typedef __attribute__((ext_vector_type(4))) int int4v;

union frag_u { short8 s8; u64 u[2]; };

__device__ __forceinline__ float clip_coord(float v) {
    return fminf(fmaxf(v, 0.0f), 159.9999f);
}
__device__ __forceinline__ float sigmoidf(float v) {
    return 1.0f / (1.0f + expf(-v));
}
__device__ __forceinline__ unsigned short f2bf(float f) {   // RNE
    unsigned u = __float_as_uint(f);
    return (unsigned short)((u + 0x7FFFu + ((u >> 16) & 1u)) >> 16);
}
__device__ __forceinline__ float bf2f(unsigned short h) {
    return __uint_as_float((unsigned)h << 16);
}

// ---------------------------------------------------------------------------
// Pre-pack w1 into the LDS image consumed by conv1_mfma:
//   Wpack[octile 12][icc 8][tap 9][ocl 32][64 shorts, slot-permuted, NO pad]
// ---------------------------------------------------------------------------
__global__ void wpack_kernel(const float* __restrict__ w1, short* __restrict__ wpk) {
    int e = blockIdx.x * 256 + threadIdx.x;      // 12*8*9*32*64 = 1,769,472 exact
    int row = e >> 6, sp = e & 63;
    int ocl = row & 31;
    int tap = (row >> 5) % 9;
    int icc = (row / 288) & 7;
    int octile = row / 2304;
    int s = (sp >> 2) ^ (ocl & 15);              // logical slot
    int ql = s * 4 + (sp & 3);                   // logical short index 0..63
    int term = ql >> 5, icl = ql & 31;
    int oc = octile * 32 + ocl, ic = icc * 32 + icl;
    float a = w1[((size_t)oc * CIN + ic) * 9 + tap];
    unsigned short hi = f2bf(a);
    wpk[e] = (term == 0) ? (short)hi : (short)f2bf(a - bf2f(hi));
}

// ---------------------------------------------------------------------------
// conv1 via MFMA implicit GEMM, 2-term bf16 split (4 products).
// Block: 32 oc x (16x16) px tile.  1D grid 4800 with XCD swizzle: each XCD
// (bid&7) owns tiles {xcd, xcd+8, ...} and runs all 12 octiles of a tile
// consecutively -> feat halo stays in that XCD's L2 (fetch ~once).
// B (feat) is register-prefetched one chunk ahead: loads issue before the
// 9-tap MFMA loop, overlapping global latency with compute.
// Accumulation order bitwise == rounds 6/7.
// ---------------------------------------------------------------------------
__global__ __launch_bounds__(256, 2) void conv1_mfma(
    const float* __restrict__ feat, const short* __restrict__ wpk,
    const float* __restrict__ b1, const float* __restrict__ gamma,
    const float* __restrict__ beta, const float* __restrict__ mean,
    const float* __restrict__ var, float* __restrict__ y1) {
    const int bid   = blockIdx.x;                 // 0..4799
    const int slot  = bid >> 3;                   // 0..599
    const int tile  = (bid & 7) + ((slot / 12) << 3);   // XCD-local tile set
    const int octile = slot - (slot / 12) * 12;   // 0..11
    const int bb = tile / 100, tt = tile % 100;
    const int ty = (tt / 10) * 16, tx = (tt % 10) * 16;
    const int oc0 = octile * 32;
    const int tid  = threadIdx.x;
    const int w    = tid >> 6;              // wave: px rows w*4..w*4+3
    const int lane = tid & 63;
    const int quad = lane >> 4;
    const int l15  = lane & 15;

    __shared__ short Alds[288 * 64];        // [tap*32+ocl][64 sh, perm'd] 36864 B
    __shared__ short Blds[324 * 68];        // [hy*18+hx][t0 32|t1 32|pad] 44064 B

    int aoff[2][2];
#pragma unroll
    for (int t = 0; t < 2; ++t)
#pragma unroll
        for (int h = 0; h < 2; ++h)
            aoff[t][h] = l15 * 128 + (((t * 8 + quad * 2 + h) ^ l15) * 8);

    f32x4 acc[2][4];
#pragma unroll
    for (int mi = 0; mi < 2; ++mi)
#pragma unroll
        for (int nj = 0; nj < 4; ++nj) acc[mi][nj] = (f32x4){0.f, 0.f, 0.f, 0.f};

    const int4v* asrc_base = (const int4v*)wpk + (size_t)(octile * 8) * 2304;
    unsigned* Bd = (unsigned*)Blds;

    // B prefetch registers: 21 iters x 2 floats
    float pv0[21], pv1[21];

    // ---- prefetch chunk 0
#pragma unroll
    for (int ii = 0; ii < 21; ++ii) {
        int i = tid + ii * 256;
        if (i < 5184) {
            int icp = i / 324, hp = i - icp * 324;
            int hy = hp / 18, hx = hp - hy * 18;
            int gy = ty + hy - 1, gx = tx + hx - 1;
            bool valid = ((unsigned)gy < IMG) && ((unsigned)gx < IMG);
            const float* fs = feat + ((size_t)(bb * CIN + icp * 2)) * HWSZ
                                   + (valid ? (gy * IMG + gx) : 0);
            pv0[ii] = valid ? fs[0]    : 0.0f;
            pv1[ii] = valid ? fs[HWSZ] : 0.0f;
        }
    }

#pragma unroll 1
    for (int icc = 0; icc < 8; ++icc) {
        __syncthreads();                    // prev chunk's frag reads complete
        // ---- stage A: 36864 B = 2304 int4 (wpk is L2-hot)
        {
            const int4v* asrc = asrc_base + (size_t)icc * 2304;
            int4v* adst = (int4v*)Alds;
#pragma unroll
            for (int i = 0; i < 9; ++i)
                adst[tid + i * 256] = asrc[tid + i * 256];
        }
        // ---- write prefetched B: convert + split to LDS
#pragma unroll
        for (int ii = 0; ii < 21; ++ii) {
            int i = tid + ii * 256;
            if (i < 5184) {
                int icp = i / 324, hp = i - icp * 324;
                float v0 = pv0[ii], v1 = pv1[ii];
                unsigned short h0 = f2bf(v0), h1 = f2bf(v1);
                unsigned short m0 = f2bf(v0 - bf2f(h0)), m1 = f2bf(v1 - bf2f(h1));
                Bd[hp * 34 + icp]      = (unsigned)h0 | ((unsigned)h1 << 16);
                Bd[hp * 34 + 16 + icp] = (unsigned)m0 | ((unsigned)m1 << 16);
            }
        }
        __syncthreads();

        // ---- issue next chunk's B loads (overlap with compute below)
        if (icc < 7) {
#pragma unroll
            for (int ii = 0; ii < 21; ++ii) {
                int i = tid + ii * 256;
                if (i < 5184) {
                    int icp = i / 324, hp = i - icp * 324;
                    int hy = hp / 18, hx = hp - hy * 18;
                    int gy = ty + hy - 1, gx = tx + hx - 1;
                    bool valid = ((unsigned)gy < IMG) && ((unsigned)gx < IMG);
                    const float* fs = feat
                        + ((size_t)(bb * CIN + (icc + 1) * 32 + icp * 2)) * HWSZ
                        + (valid ? (gy * IMG + gx) : 0);
                    pv0[ii] = valid ? fs[0]    : 0.0f;
                    pv1[ii] = valid ? fs[HWSZ] : 0.0f;
                }
            }
        }

#pragma unroll
        for (int tap = 0; tap < 9; ++tap) {
            const int sy = tap / 3, sx = tap % 3;
            frag_u Af[2][2], Bf[2][4];
#pragma unroll
            for (int t = 0; t < 2; ++t) {
#pragma unroll
                for (int mi = 0; mi < 2; ++mi) {
                    const char* base = (const char*)Alds + (tap * 32 + mi * 16) * 128;
                    Af[t][mi].u[0] = *(const u64*)(base + aoff[t][0]);
                    Af[t][mi].u[1] = *(const u64*)(base + aoff[t][1]);
                }
#pragma unroll
                for (int nj = 0; nj < 4; ++nj) {
                    int pos = (w * 4 + nj + sy) * 18 + (l15 + sx);
                    const short* bp = &Blds[pos * 68 + t * 32 + quad * 8];
                    Bf[t][nj].u[0] = *(const u64*)bp;
                    Bf[t][nj].u[1] = *(const u64*)(bp + 4);
                }
            }
#pragma unroll
            for (int mi = 0; mi < 2; ++mi)
#pragma unroll
                for (int nj = 0; nj < 4; ++nj) {
                    acc[mi][nj] = __builtin_amdgcn_mfma_f32_16x16x32_bf16(
                        Af[0][mi].s8, Bf[0][nj].s8, acc[mi][nj], 0, 0, 0);
                    acc[mi][nj] = __builtin_amdgcn_mfma_f32_16x16x32_bf16(
                        Af[0][mi].s8, Bf[1][nj].s8, acc[mi][nj], 0, 0, 0);
                    acc[mi][nj] = __builtin_amdgcn_mfma_f32_16x16x32_bf16(
                        Af[1][mi].s8, Bf[0][nj].s8, acc[mi][nj], 0, 0, 0);
                    acc[mi][nj] = __builtin_amdgcn_mfma_f32_16x16x32_bf16(
                        Af[1][mi].s8, Bf[1][nj].s8, acc[mi][nj], 0, 0, 0);
                }
        }
    }

    // ---- epilogue: BN + ReLU.  C/D: col(l15)=px col, row(quad*4+r)=oc.
#pragma unroll
    for (int nj = 0; nj < 4; ++nj) {
        const int gy = ty + w * 4 + nj, gx = tx + l15;
#pragma unroll
        for (int mi = 0; mi < 2; ++mi)
#pragma unroll
            for (int r = 0; r < 4; ++r) {
                const int oc = oc0 + mi * 16 + quad * 4 + r;
                float v = acc[mi][nj][r] + b1[oc];
                v = (v - mean[oc]) * (gamma[oc] / sqrtf(var[oc] + 1e-5f)) + beta[oc];
                y1[((size_t)(bb * COUT1 + oc)) * HWSZ + gy * IMG + gx] = fmaxf(v, 0.0f);
            }
    }
}

// ---------------------------------------------------------------------------
// conv2: grouped 3x3, only the SEL channels; sigmoid where needed; -> d_out.
// ---------------------------------------------------------------------------
__global__ __launch_bounds__(256, 2) void conv2_kernel(
    const float* __restrict__ y1, const float* __restrict__ w2,
    const float* __restrict__ b2, float* __restrict__ out) {
    const int KH[6]   = {1, 1, 2, 1, 2, 4};
    const int REG[6]  = {OFF_LMAP, OFF_JMAP, OFF_JOFF, OFF_CMAP, OFF_COFF, OFF_LVEC};
    const int SIGF[6] = {1, 1, 0, 1, 0, 0};

    const int bz = blockIdx.z;
    const int b  = bz / 6;
    const int h  = bz % 6;
    const int k  = KH[h];
    const int tx = blockIdx.x * 16, ty = blockIdx.y * 16;
    const int lx = threadIdx.x, ly = threadIdx.y;
    const int tid = ly * 16 + lx;

    __shared__ float tin[16][18][33];
    float acc[4] = {0.0f, 0.0f, 0.0f, 0.0f};

    const float* yb = y1 + ((size_t)(b * COUT1 + h * 64)) * HWSZ;

    for (int ic0 = 0; ic0 < 64; ic0 += 16) {
        __syncthreads();
        for (int i = tid; i < 5184; i += 256) {
            int c = i / 324, rem = i - c * 324;
            int r = rem / 18, col = rem - r * 18;
            int gy = ty - 1 + r, gx = tx - 1 + col;
            float v = 0.0f;
            if (gy >= 0 && gy < IMG && gx >= 0 && gx < IMG)
                v = yb[(size_t)(ic0 + c) * HWSZ + gy * IMG + gx];
            tin[c][r][col] = v;
        }
        __syncthreads();
#pragma unroll 4
        for (int c = 0; c < 16; ++c) {
            float n0 = tin[c][ly][lx],     n1 = tin[c][ly][lx + 1],     n2 = tin[c][ly][lx + 2];
            float n3 = tin[c][ly + 1][lx], n4 = tin[c][ly + 1][lx + 1], n5 = tin[c][ly + 1][lx + 2];
            float n6 = tin[c][ly + 2][lx], n7 = tin[c][ly + 2][lx + 1], n8 = tin[c][ly + 2][lx + 2];
#pragma unroll
            for (int o = 0; o < 4; ++o) {
                if (o < k) {
                    const float* wp = w2 + ((size_t)((h * 4 + o) * 64 + (ic0 + c))) * 9;
                    acc[o] = fmaf(n0, wp[0], fmaf(n1, wp[1], fmaf(n2, wp[2],
                             fmaf(n3, wp[3], fmaf(n4, wp[4], fmaf(n5, wp[5],
                             fmaf(n6, wp[6], fmaf(n7, wp[7], fmaf(n8, wp[8], acc[o])))))))));
                }
            }
        }
    }

    const int p = (ty + ly) * IMG + tx + lx;
    for (int o = 0; o < k; ++o) {
        float v = acc[o] + b2[h * 4 + o];
        if (SIGF[h]) v = sigmoidf(v);
        out[REG[h] + ((size_t)(b * k + o)) * HWSZ + p] = v;
    }
}

// ---------------------------------------------------------------------------
// NMS on jmap + pack sort keys (value_bits<<32 | ~index  == lax.top_k order).
// ---------------------------------------------------------------------------
__global__ void nms_pack_kernel(const float* __restrict__ out,
                                u64* __restrict__ jsort,
                                u64* __restrict__ csort) {
    const int g = blockIdx.x;           // 0..399
    const int b = g / 100, q = g % 100;
    const int p = q * 256 + threadIdx.x;
    const float* jm = out + OFF_JMAP + (size_t)b * HWSZ;
    const float* cm = out + OFF_CMAP + (size_t)b * HWSZ;

    const int x = p % IMG, y = p / IMG;
    float v = jm[p];
    float mx = v;
#pragma unroll
    for (int dy = -1; dy <= 1; ++dy)
#pragma unroll
        for (int dx = -1; dx <= 1; ++dx) {
            int nx = x + dx, ny = y + dy;
            if (nx >= 0 && nx < IMG && ny >= 0 && ny < IMG)
                mx = fmaxf(mx, jm[ny * IMG + nx]);
        }
    float nmsv = (v == mx) ? v : 0.0f;

    u64 tagj = ((u64)__float_as_uint(nmsv) << 32)
             | (u64)(0xFFFFFFFFu - (unsigned)p);
    u64 tagc = ((u64)__float_as_uint(cm[p]) << 32)
             | (u64)(0xFFFFFFFFu - (unsigned)p);
    jsort[(size_t)b * 32768 + p] = tagj;
    csort[(size_t)b * 32768 + p] = tagc;
    if (q < 28) {                        // pad 25600..32767 with minimal keys
        int pp = 25600 + q * 256 + threadIdx.x;
        jsort[(size_t)b * 32768 + pp] = 0ull;
        csort[(size_t)b * 32768 + pp] = 0ull;
    }
}

// ---------------------------------------------------------------------------
// Hybrid bitonic sort, descending, 8 arrays x 32768 u64.
// ---------------------------------------------------------------------------
__global__ __launch_bounds__(1024) void sort64_ldsA(u64* __restrict__ buf) {
    __shared__ u64 s[8192];
    const size_t base = (size_t)blockIdx.x * 8192;   // 32 chunks (8 arrays x 4)
    const int cbase = (blockIdx.x & 3) * 8192;       // chunk offset within array
    for (int i = threadIdx.x; i < 8192; i += 1024) s[i] = buf[base + i];
    for (int k = 2; k <= 8192; k <<= 1)
        for (int j = k >> 1; j > 0; j >>= 1) {
            __syncthreads();
            for (int t = threadIdx.x; t < 4096; t += 1024) {
                int i = ((t & ~(j - 1)) << 1) | (t & (j - 1));
                int l = i | j;
                bool desc = (((i + cbase) & k) == 0);
                u64 x = s[i], y = s[l];
                if (desc ? (x < y) : (x > y)) { s[i] = y; s[l] = x; }
            }
        }
    __syncthreads();
    for (int i = threadIdx.x; i < 8192; i += 1024) buf[base + i] = s[i];
}

__global__ void sort64_gstep(u64* __restrict__ buf, int k, int j) {
    int t = blockIdx.x * 256 + threadIdx.x;          // 8 arrays * 16384 pairs
    int arr = t >> 14, p = t & 16383;
    int i = ((p & ~(j - 1)) << 1) | (p & (j - 1));
    int l = i | j;
    bool desc = ((i & k) == 0);
    u64* a = buf + (size_t)arr * 32768;
    u64 x = a[i], y = a[l];
    if (desc ? (x < y) : (x > y)) { a[i] = y; a[l] = x; }
}

__global__ __launch_bounds__(1024) void sort64_ldsB(u64* __restrict__ buf, int k) {
    __shared__ u64 s[8192];
    const size_t base = (size_t)blockIdx.x * 8192;
    const int cbase = (blockIdx.x & 3) * 8192;
    for (int i = threadIdx.x; i < 8192; i += 1024) s[i] = buf[base + i];
    for (int j = 4096; j > 0; j >>= 1) {
        __syncthreads();
        for (int t = threadIdx.x; t < 4096; t += 1024) {
            int i = ((t & ~(j - 1)) << 1) | (t & (j - 1));
            int l = i | j;
            bool desc = (((i + cbase) & k) == 0);
            u64 x = s[i], y = s[l];
            if (desc ? (x < y) : (x > y)) { s[i] = y; s[l] = x; }
        }
    }
    __syncthreads();
    for (int i = threadIdx.x; i < 8192; i += 1024) buf[base + i] = s[i];
}

// Full-LDS bitonic sort, ascending, 8192 int keys (one array per block).
__global__ __launch_bounds__(1024) void sort32_lds(int* __restrict__ buf) {
    __shared__ int s[8192];
    int* a = buf + (size_t)blockIdx.x * 8192;
    for (int i = threadIdx.x; i < 8192; i += 1024) s[i] = a[i];
    for (int k = 2; k <= 8192; k <<= 1)
        for (int j = k >> 1; j > 0; j >>= 1) {
            __syncthreads();
            for (int t = threadIdx.x; t < 4096; t += 1024) {
                int i = ((t & ~(j - 1)) << 1) | (t & (j - 1));
                int l = i | j;
                bool asc = ((i & k) == 0);
                int x = s[i], y = s[l];
                if (asc ? (x > y) : (x < y)) { s[i] = y; s[l] = x; }
            }
        }
    __syncthreads();
    for (int i = threadIdx.x; i < 8192; i += 1024) a[i] = s[i];
}

// Top-300 junctions: coordinates + validity.
__global__ void junction_kernel(const u64* __restrict__ jsort,
                                const float* __restrict__ out,
                                float* __restrict__ junc, int* __restrict__ jvalid) {
    const int b = blockIdx.x;
    const int t = threadIdx.x;
    if (t >= 300) return;
    u64 key = jsort[(size_t)b * 32768 + t];
    float score  = __uint_as_float((unsigned)(key >> 32));
    unsigned idx = 0xFFFFFFFFu - (unsigned)(key & 0xFFFFFFFFull);
    const float* j0 = out + OFF_JOFF + (size_t)(b * 2) * HWSZ;
    const float* j1 = j0 + HWSZ;
    float jx = (float)(idx % IMG) + j0[idx] + 0.5f;
    float jy = (float)(idx / IMG) + j1[idx] + 0.5f;
    junc[(size_t)(b * 300 + t) * 2]     = clip_coord(jx);
    junc[(size_t)(b * 300 + t) * 2 + 1] = clip_coord(jy);
    jvalid[b * 300 + t] = (score >= 0.008f) ? 1 : 0;
}

// Top-5000 centers -> line endpoints -> nearest-junction keys.
__global__ void lines_kernel(const u64* __restrict__ csort,
                             const float* __restrict__ junc,
                             const int* __restrict__ jvalid,
                             const float* __restrict__ out,
                             int* __restrict__ lkeys) {
    const int b = blockIdx.y;
    const int t = blockIdx.x * 256 + threadIdx.x;

    __shared__ float jx[300], jy[300];
    __shared__ int jv[300];
    for (int i = threadIdx.x; i < 300; i += 256) {
        jx[i] = junc[(size_t)(b * 300 + i) * 2];
        jy[i] = junc[(size_t)(b * 300 + i) * 2 + 1];
        jv[i] = jvalid[b * 300 + i];
    }
    __syncthreads();

    if (t >= 8192) return;
    if (t >= 5000) { lkeys[b * 8192 + t] = 0x7FFFFFFF; return; }

    u64 key = csort[(size_t)b * 32768 + t];
    unsigned idx = 0xFFFFFFFFu - (unsigned)(key & 0xFFFFFFFFull);
    const float* c0 = out + OFF_COFF + (size_t)(b * 2) * HWSZ;
    const float* c1 = c0 + HWSZ;
    const float* lv = out + OFF_LVEC + (size_t)(b * 4) * HWSZ;

    float cx = (float)(idx % IMG) + c0[idx] + 0.5f;
    float cy = (float)(idx / IMG) + c1[idx] + 0.5f;
    float e0x = clip_coord(cx + lv[idx]);
    float e0y = clip_coord(cy + lv[HWSZ + idx]);
    float e1x = clip_coord(cx + lv[2 * HWSZ + idx]);
    float e1y = clip_coord(cy + lv[3 * HWSZ + idx]);

    float m1 = 1e18f, m2 = 1e18f;
    int i1 = 0, i2 = 0;
    for (int j = 0; j < 300; ++j) {
        if (jv[j]) {
            float dx = e0x - jx[j], dy = e0y - jy[j];
            float d = dx * dx + dy * dy;
            if (d < m1) { m1 = d; i1 = j; }
            dx = e1x - jx[j]; dy = e1y - jy[j];
            d = dx * dx + dy * dy;
            if (d < m2) { m2 = d; i2 = j; }
        }
    }
    int imin = min(i1, i2), imax = max(i1, i2);
    lkeys[b * 8192 + t] = (i1 != i2) ? (imin * 300 + imax) : BIGK;
}

// Dedup sorted keys -> line segments + mask.
__global__ void finalize_kernel(const int* __restrict__ lkeys,
                                const float* __restrict__ junc,
                                float* __restrict__ out) {
    const int b = blockIdx.y;
    const int t = blockIdx.x * 256 + threadIdx.x;
    if (t >= 5000) return;
    const int* lk = lkeys + b * 8192;
    int sk = lk[t];
    bool first = ((t == 0) || (sk != lk[t - 1])) && (sk < BIGK);
    int a  = first ? sk / 300 : 0;
    int bb = first ? sk % 300 : 0;
    float p0x = junc[(size_t)(b * 300 + a) * 2];
    float p0y = junc[(size_t)(b * 300 + a) * 2 + 1];
    float p1x = junc[(size_t)(b * 300 + bb) * 2];
    float p1y = junc[(size_t)(b * 300 + bb) * 2 + 1];
    if (p0y > p1y) {
        float tx = p0x; p0x = p1x; p1x = tx;
        float ty = p0y; p0y = p1y; p1y = ty;
    }
    size_t base = OFF_LOI + (size_t)(b * 5000 + t) * 4;
    out[base]     = p0x;
    out[base + 1] = p0y;
    out[base + 2] = p1x;
    out[base + 3] = p1y;
    out[OFF_MASK + b * 5000 + t] = first ? 1.0f : 0.0f;
}

extern "C" void kernel_launch(void* const* d_in, const int* in_sizes, int n_in,
                              void* d_out, int out_size, void* d_ws, size_t ws_size,
                              hipStream_t stream) {
    const float* feat  = (const float*)d_in[0];
    const float* w1    = (const float*)d_in[1];
    const float* b1    = (const float*)d_in[2];
    const float* gamma = (const float*)d_in[3];
    const float* beta  = (const float*)d_in[4];
    const float* mean  = (const float*)d_in[5];
    const float* var   = (const float*)d_in[6];
    const float* w2    = (const float*)d_in[7];
    const float* b2    = (const float*)d_in[8];
    float* out = (float*)d_out;
    char*  ws  = (char*)d_ws;

    if (ws_size < WS_NEED) return;   // ~163 MB needed

    float* y1 = (float*)(ws + WS_Y1);
    u64* jsort = (u64*)(ws + WS_JSORT);
    float* junc = (float*)(ws + WS_JUNC);
    int* jvalid = (int*)(ws + WS_JVAL);
    int* lkeys  = (int*)(ws + WS_LKEY);
    u64* csort = (u64*)(ws + WS_CSORT);
    short* wpk = (short*)(ws + WS_WPK);

    // 0. pre-split/pack conv1 weights into MFMA staging layout (perm baked in)
    wpack_kernel<<<dim3(6912), dim3(256), 0, stream>>>(w1, wpk);

    // 1. conv1 + BN + ReLU -> y1  (MFMA implicit GEMM, XCD-swizzled 1D grid)
    conv1_mfma<<<dim3(4800), dim3(256), 0, stream>>>(
        feat, wpk, b1, gamma, beta, mean, var, y1);

    // 2. conv2 (grouped, SEL channels only) -> maps in d_out
    conv2_kernel<<<dim3(10, 10, NB * 6), dim3(16, 16), 0, stream>>>(y1, w2, b2, out);

    // 3. NMS + pack sort keys
    nms_pack_kernel<<<dim3(NB * 100), dim3(256), 0, stream>>>(out, jsort, csort);

    // 4. hybrid bitonic sort of 8 u64 arrays (4 jmap + 4 cmap, contiguous)
    sort64_ldsA<<<dim3(32), dim3(1024), 0, stream>>>(jsort);
    sort64_gstep<<<dim3(512), dim3(256), 0, stream>>>(jsort, 16384, 8192);
    sort64_ldsB<<<dim3(32), dim3(1024), 0, stream>>>(jsort, 16384);
    sort64_gstep<<<dim3(512), dim3(256), 0, stream>>>(jsort, 32768, 16384);
    sort64_gstep<<<dim3(512), dim3(256), 0, stream>>>(jsort, 32768, 8192);
    sort64_ldsB<<<dim3(32), dim3(1024), 0, stream>>>(jsort, 32768);

    // 5. junctions
    junction_kernel<<<dim3(NB), dim3(320), 0, stream>>>(jsort, out, junc, jvalid);

    // 6. line keys
    lines_kernel<<<dim3(32, NB), dim3(256), 0, stream>>>(csort, junc, jvalid, out, lkeys);

    // 7. sort line keys ascending (full LDS)
    sort32_lds<<<dim3(NB), dim3(1024), 0, stream>>>(lkeys);

    // 8. dedup + emit loi/mask
    finalize_kernel<<<dim3(20, NB), dim3(256), 0, stream>>>(lkeys, junc, out);
}